// Round 10
// baseline (7571.317 us; speedup 1.0000x reference)
//
#include <hip/hip_runtime.h>
#include <math.h>

#define Q_ 13294
#define D_ 256
#define NLAYERS_ 6
#define MROWS 26588
#define MD ((size_t)MROWS * D_)

__device__ __forceinline__ void decode_row(int gr, int& b, int& l, int& p) {
    b = (gr >= Q_) ? 1 : 0;
    int q = gr - b * Q_;
    if (q < 10000)      { l = 0; p = q; }
    else if (q < 12500) { l = 1; p = q - 10000; }
    else if (q < 13125) { l = 2; p = q - 12500; }
    else                { l = 3; p = q - 13125; }
}

// ---------------------------------------------------------------------------
// Flatten src (fp32 transpose): X[b, s_l+p, d] = src_l[b,d,p]
// grid (313, 8, 8), block (32,8)
// ---------------------------------------------------------------------------
__global__ __launch_bounds__(256)
void flatten_kernel(const float* __restrict__ s0, const float* __restrict__ s1,
                    const float* __restrict__ s2, const float* __restrict__ s3,
                    float* __restrict__ X)
{
    const int lHW[4] = {10000, 2500, 625, 169};
    const int lS[4]  = {0, 10000, 12500, 13125};
    int z = blockIdx.z;
    int l = z & 3, b = z >> 2;
    int HW = lHW[l];
    int p0 = blockIdx.x * 32;
    if (p0 >= HW) return;
    int d0 = blockIdx.y * 32;
    const float* src = (l == 0) ? s0 : (l == 1) ? s1 : (l == 2) ? s2 : s3;
    int tx = threadIdx.x, ty = threadIdx.y;
    __shared__ float t[32][33];
    #pragma unroll
    for (int i = 0; i < 4; ++i) {
        int d = d0 + ty + 8 * i, p = p0 + tx;
        t[ty + 8 * i][tx] = (p < HW) ? src[(size_t)(b * D_ + d) * HW + p] : 0.f;
    }
    __syncthreads();
    #pragma unroll
    for (int i = 0; i < 4; ++i) {
        int p = p0 + ty + 8 * i, d = d0 + tx;
        if (p < HW)
            X[(size_t)(b * Q_ + lS[l] + p) * D_ + d] = t[tx][ty + 8 * i];
    }
}

// ---------------------------------------------------------------------------
// qmake: Tq[r, d] = X[row0+r, d] + pos_l[b, d, p] + level_embed[l, d]  (fp32)
// 64 threads per row, 4 d's per thread.
// ---------------------------------------------------------------------------
__global__ __launch_bounds__(256)
void qmake_kernel(const float* __restrict__ X,
                  const float* __restrict__ p0_, const float* __restrict__ p1_,
                  const float* __restrict__ p2_, const float* __restrict__ p3_,
                  const float* __restrict__ le,
                  float* __restrict__ Tq, int row0, int mc)
{
    const int lHW[4] = {10000, 2500, 625, 169};
    int gid = blockIdx.x * 256 + threadIdx.x;
    int r = gid >> 6, d4 = gid & 63;
    if (r >= mc) return;
    int gr = row0 + r;
    int b, l, p;
    decode_row(gr, b, l, p);
    const float* pos = (l == 0) ? p0_ : (l == 1) ? p1_ : (l == 2) ? p2_ : p3_;
    int HW = lHW[l];
    int d = d4 * 4;
    float4 xv = *(const float4*)(X + (size_t)gr * D_ + d);
    float4 o;
    o.x = xv.x + pos[(size_t)(b * D_ + d + 0) * HW + p] + le[l * D_ + d + 0];
    o.y = xv.y + pos[(size_t)(b * D_ + d + 1) * HW + p] + le[l * D_ + d + 1];
    o.z = xv.z + pos[(size_t)(b * D_ + d + 2) * HW + p] + le[l * D_ + d + 2];
    o.w = xv.w + pos[(size_t)(b * D_ + d + 3) * HW + p] + le[l * D_ + d + 3];
    *(float4*)(Tq + (size_t)r * D_ + d) = o;
}

// ---------------------------------------------------------------------------
// fp32 GEMM: C[M,N](ldc) = A[M,K] @ B[K,N](ldb) + bias[N]
// (+fp32 residual R at ldc, optional relu).
// BM=BN=64, BK=16, 256 threads, 4x4 acc/thread.
// ---------------------------------------------------------------------------
__global__ __launch_bounds__(256)
void gemm_f(const float* __restrict__ A, const float* __restrict__ Bm,
            const float* __restrict__ bias,
            const float* __restrict__ R, float* __restrict__ C,
            int M, int N, int K, int ldb, int ldc, int relu)
{
    __shared__ float As[16][68];
    __shared__ float Bs[16][64];
    int t = threadIdx.x;
    int m0 = blockIdx.x * 64, n0 = blockIdx.y * 64;
    int tx = t & 15, ty = t >> 4;
    int arow = t >> 2, ac4 = t & 3;
    int brow = t >> 4, bc4 = t & 15;
    float acc[4][4] = {};

    for (int k0 = 0; k0 < K; k0 += 16) {
        int gr = m0 + arow;
        float4 av = make_float4(0.f, 0.f, 0.f, 0.f);
        if (gr < M) av = *(const float4*)(A + (size_t)gr * K + k0 + ac4 * 4);
        As[ac4 * 4 + 0][arow] = av.x;
        As[ac4 * 4 + 1][arow] = av.y;
        As[ac4 * 4 + 2][arow] = av.z;
        As[ac4 * 4 + 3][arow] = av.w;
        float4 bv = *(const float4*)(Bm + (size_t)(k0 + brow) * ldb + n0 + bc4 * 4);
        *(float4*)&Bs[brow][bc4 * 4] = bv;
        __syncthreads();
        #pragma unroll
        for (int k = 0; k < 16; ++k) {
            float4 a4 = *(const float4*)&As[k][ty * 4];
            float4 b4 = *(const float4*)&Bs[k][tx * 4];
            float a[4] = {a4.x, a4.y, a4.z, a4.w};
            float bb[4] = {b4.x, b4.y, b4.z, b4.w};
            #pragma unroll
            for (int i = 0; i < 4; ++i)
                #pragma unroll
                for (int j = 0; j < 4; ++j)
                    acc[i][j] += a[i] * bb[j];
        }
        __syncthreads();
    }

    #pragma unroll
    for (int i = 0; i < 4; ++i) {
        int row = m0 + ty * 4 + i;
        if (row >= M) continue;
        float cp[4];
        #pragma unroll
        for (int j = 0; j < 4; ++j)
            cp[j] = acc[i][j] + bias[n0 + tx * 4 + j];
        if (R) {
            float4 r4 = *(const float4*)(R + (size_t)row * ldc + n0 + tx * 4);
            cp[0] += r4.x; cp[1] += r4.y; cp[2] += r4.z; cp[3] += r4.w;
        }
        if (relu) {
            #pragma unroll
            for (int j = 0; j < 4; ++j) cp[j] = fmaxf(cp[j], 0.f);
        }
        *(float4*)(C + (size_t)row * ldc + n0 + tx * 4) =
            make_float4(cp[0], cp[1], cp[2], cp[3]);
    }
}

// ---------------------------------------------------------------------------
// LayerNorm chunk: X[row0+r] = LN(PRE[r]) * g + b (all fp32). one wave per row.
// ---------------------------------------------------------------------------
__global__ __launch_bounds__(256)
void ln_kernel(const float* __restrict__ P, const float* __restrict__ g,
               const float* __restrict__ b, float* __restrict__ Xo,
               int row0, int mc)
{
    int wave = threadIdx.x >> 6, lane = threadIdx.x & 63;
    int r = blockIdx.x * 4 + wave;
    if (r >= mc) return;
    const float* x = P + (size_t)r * D_;
    float4 v = *(const float4*)(x + lane * 4);
    float s = v.x + v.y + v.z + v.w;
    float sq = v.x * v.x + v.y * v.y + v.z * v.z + v.w * v.w;
    #pragma unroll
    for (int o = 32; o > 0; o >>= 1) {
        s += __shfl_xor(s, o, 64);
        sq += __shfl_xor(sq, o, 64);
    }
    float mean = s * (1.f / 256.f);
    float var = fmaxf(sq * (1.f / 256.f) - mean * mean, 0.f);
    float rs = rsqrtf(var + 1e-5f);
    float4 gv = *(const float4*)(g + lane * 4);
    float4 bv = *(const float4*)(b + lane * 4);
    float4 o;
    o.x = (v.x - mean) * rs * gv.x + bv.x;
    o.y = (v.y - mean) * rs * gv.y + bv.y;
    o.z = (v.z - mean) * rs * gv.z + bv.z;
    o.w = (v.w - mean) * rs * gv.w + bv.w;
    *(float4*)(Xo + (size_t)(row0 + r) * D_ + lane * 4) = o;
}

// ---------------------------------------------------------------------------
// Deformable sampling per chunk row: softmax(16 attn logits) + 16-point
// bilinear gather, branchless clip+valid (exact jnp.clip/take semantics).
// VAL per level in V0..V3, layout [b][p_local][256] fp32 (in src buffers).
// block = one row; 256 threads = 8 heads x 32 hd.
// OFF row (ld 256): [h][l][p][2];  ATT row (ld 128): [h][l*4+p]
// ---------------------------------------------------------------------------
__global__ __launch_bounds__(256)
void sample_kernel(const float* __restrict__ OFF, const float* __restrict__ ATT,
                   const float* __restrict__ V0, const float* __restrict__ V1,
                   const float* __restrict__ V2, const float* __restrict__ V3,
                   float* __restrict__ OUT, int row0)
{
    const int lH[4]  = {100, 50, 25, 13};
    const int lW[4]  = {100, 50, 25, 13};
    const int lHW[4] = {10000, 2500, 625, 169};

    int r = blockIdx.x;
    int gr = row0 + r;
    int b, lq, p;
    decode_row(gr, b, lq, p);
    int h = threadIdx.x >> 5, hd = threadIdx.x & 31;

    int rw = lW[lq];
    int prow = p / rw, pcol = p - prow * rw;
    float refx = (pcol + 0.5f) / (float)lW[lq];
    float refy = (prow + 0.5f) / (float)lH[lq];

    const float* offp = OFF + (size_t)r * 256 + h * 32;
    const float* attp = ATT + (size_t)r * 128 + h * 16;

    float w16[16];
    float mx = -1e30f;
    #pragma unroll
    for (int j = 0; j < 16; ++j) { w16[j] = attp[j]; mx = fmaxf(mx, w16[j]); }
    float ssum = 0.f;
    #pragma unroll
    for (int j = 0; j < 16; ++j) { w16[j] = __expf(w16[j] - mx); ssum += w16[j]; }
    float inv = 1.f / ssum;

    float o = 0.f;
    #pragma unroll
    for (int l = 0; l < 4; ++l) {
        int Wl = lW[l], Hl = lH[l];
        const float* vl = ((l == 0) ? V0 : (l == 1) ? V1 : (l == 2) ? V2 : V3)
                          + ((size_t)b * lHW[l]) * D_ + h * 32 + hd;
        #pragma unroll
        for (int pp = 0; pp < 4; ++pp) {
            float ox = offp[l * 8 + pp * 2 + 0];
            float oy = offp[l * 8 + pp * 2 + 1];
            float xf = (refx + ox / (float)Wl) * Wl - 0.5f;
            float yf = (refy + oy / (float)Hl) * Hl - 0.5f;
            xf = fmaxf(fminf(xf, 1.0e6f), -1.0e6f);
            yf = fmaxf(fminf(yf, 1.0e6f), -1.0e6f);
            float x0f = floorf(xf), y0f = floorf(yf);
            float fx = xf - x0f, fy = yf - y0f;
            int x0 = (int)x0f, y0 = (int)y0f;
            int x1 = x0 + 1, y1 = y0 + 1;
            int x0c = min(max(x0, 0), Wl - 1), x1c = min(max(x1, 0), Wl - 1);
            int y0c = min(max(y0, 0), Hl - 1), y1c = min(max(y1, 0), Hl - 1);
            float vx0 = (x0 >= 0 && x0 < Wl) ? 1.f : 0.f;
            float vx1 = (x1 >= 0 && x1 < Wl) ? 1.f : 0.f;
            float vy0 = (y0 >= 0 && y0 < Hl) ? 1.f : 0.f;
            float vy1 = (y1 >= 0 && y1 < Hl) ? 1.f : 0.f;
            float g00 = vl[(size_t)(y0c * Wl + x0c) * D_];
            float g10 = vl[(size_t)(y0c * Wl + x1c) * D_];
            float g01 = vl[(size_t)(y1c * Wl + x0c) * D_];
            float g11 = vl[(size_t)(y1c * Wl + x1c) * D_];
            float accv = (1.f - fx) * (1.f - fy) * vx0 * vy0 * g00
                       + fx * (1.f - fy) * vx1 * vy0 * g10
                       + (1.f - fx) * fy * vx0 * vy1 * g01
                       + fx * fy * vx1 * vy1 * g11;
            o += w16[l * 4 + pp] * inv * accv;
        }
    }
    OUT[(size_t)r * D_ + h * 32 + hd] = o;
}

extern "C" void kernel_launch(void* const* d_in, const int* in_sizes, int n_in,
                              void* d_out, int out_size, void* d_ws, size_t ws_size,
                              hipStream_t stream)
{
    // setup_inputs() dict order interleaves src/pos. Detect: dict order gives
    // in_sizes[0]==in_sizes[1] (src0,pos0 both 5.12M); signature order doesn't.
    bool interleaved = (in_sizes[0] == in_sizes[1]);
    int si[4], pi[4];
    for (int i = 0; i < 4; ++i) {
        si[i] = interleaved ? 2 * i : i;
        pi[i] = interleaved ? 2 * i + 1 : 4 + i;
    }
    const float* src0 = (const float*)d_in[si[0]];
    const float* src1 = (const float*)d_in[si[1]];
    const float* src2 = (const float*)d_in[si[2]];
    const float* src3 = (const float*)d_in[si[3]];
    const float* pos0 = (const float*)d_in[pi[0]];
    const float* pos1 = (const float*)d_in[pi[1]];
    const float* pos2 = (const float*)d_in[pi[2]];
    const float* pos3 = (const float*)d_in[pi[3]];
    const float* level_embed = (const float*)d_in[8];
    const float* Woff  = (const float*)d_in[9];
    const float* boff  = (const float*)d_in[10];
    const float* Wattn = (const float*)d_in[11];
    const float* battn = (const float*)d_in[12];
    const float* Wv = (const float*)d_in[13];
    const float* bv = (const float*)d_in[14];
    const float* Wo = (const float*)d_in[15];
    const float* bo = (const float*)d_in[16];
    const float* g1 = (const float*)d_in[17];
    const float* b1 = (const float*)d_in[18];
    const float* W1  = (const float*)d_in[19];
    const float* bb1 = (const float*)d_in[20];
    const float* W2  = (const float*)d_in[21];
    const float* bb2 = (const float*)d_in[22];
    const float* g2 = (const float*)d_in[23];
    const float* b2 = (const float*)d_in[24];

    // VAL lives in the consumed-after-flatten src input buffers (fp32,
    // exact element-count fit: B*HW_l*256 == src_l elems). Harness restores
    // inputs from pristine copies before every launch.
    float* V[4] = { (float*)d_in[si[0]], (float*)d_in[si[1]],
                    (float*)d_in[si[2]], (float*)d_in[si[3]] };

    // X (fp32 state) lives in d_out; the final LN writes the output in place.
    float* X = (float*)d_out;

    const int lHW[4] = {10000, 2500, 625, 169};
    const int lS[4]  = {0, 10000, 12500, 13125};

    // ws region R = RC*1280 floats:
    //   attention: Tq [0,256RC) OFF [256RC,512RC) ATT [512RC,640RC) PRE [1024RC,1280RC)
    //   FFN:       H1 [0,1024RC)                                    PRE [1024RC,1280RC)
    const int cand[10] = {4, 8, 16, 32, 64, 128, 256, 512, 1024, 2048};
    int NC = 2048;
    for (int i = 0; i < 10; ++i) {
        int rc = (MROWS + cand[i] - 1) / cand[i];
        size_t need = (size_t)rc * 1280 * 4 + 1024;
        if (need <= ws_size) { NC = cand[i]; break; }
    }
    const int RC = (MROWS + NC - 1) / NC;

    float* R    = (float*)d_ws;
    float* Tq   = R;
    float* OFFc = R + (size_t)RC * 256;
    float* ATTc = R + (size_t)RC * 512;
    float* PRE  = R + (size_t)RC * 1024;
    float* H1   = R;

    flatten_kernel<<<dim3(313, 8, 8), dim3(32, 8), 0, stream>>>(src0, src1, src2, src3, X);

    for (int l = 0; l < NLAYERS_; ++l) {
        const float* Woff_l  = Woff  + (size_t)l * D_ * 256;
        const float* boff_l  = boff  + (size_t)l * 256;
        const float* Wattn_l = Wattn + (size_t)l * D_ * 128;
        const float* battn_l = battn + (size_t)l * 128;
        const float* Wv_l = Wv + (size_t)l * D_ * D_;
        const float* bv_l = bv + (size_t)l * D_;
        const float* Wo_l = Wo + (size_t)l * D_ * D_;
        const float* bo_l = bo + (size_t)l * D_;
        const float* g1_l = g1 + (size_t)l * D_;
        const float* b1_l = b1 + (size_t)l * D_;
        const float* W1_l  = W1  + (size_t)l * D_ * 1024;
        const float* bb1_l = bb1 + (size_t)l * 1024;
        const float* W2_l  = W2  + (size_t)l * 1024 * D_;
        const float* bb2_l = bb2 + (size_t)l * D_;
        const float* g2_l = g2 + (size_t)l * D_;
        const float* b2_l = b2 + (size_t)l * D_;

        // VAL = X @ Wv + bv (fp32, per level/batch into src buffers)
        for (int lv = 0; lv < 4; ++lv) {
            for (int bb = 0; bb < 2; ++bb) {
                int Ml = lHW[lv];
                gemm_f<<<dim3((Ml + 63) / 64, 4), 256, 0, stream>>>(
                    X + (size_t)(bb * Q_ + lS[lv]) * D_, Wv_l, bv_l,
                    nullptr, V[lv] + (size_t)bb * lHW[lv] * D_,
                    Ml, 256, 256, 256, 256, 0);
            }
        }

        // attention, chunked
        for (int c = 0; c < NC; ++c) {
            int row0 = c * RC;
            int mc = MROWS - row0; if (mc > RC) mc = RC;
            if (mc <= 0) break;
            int mcg = (mc + 63) / 64;
            qmake_kernel<<<(mc * 64 + 255) / 256, 256, 0, stream>>>(
                X, pos0, pos1, pos2, pos3, level_embed, Tq, row0, mc);
            gemm_f<<<dim3(mcg, 4), 256, 0, stream>>>(
                Tq, Woff_l, boff_l, nullptr, OFFc, mc, 256, 256, 256, 256, 0);
            gemm_f<<<dim3(mcg, 2), 256, 0, stream>>>(
                Tq, Wattn_l, battn_l, nullptr, ATTc, mc, 128, 256, 128, 128, 0);
            sample_kernel<<<mc, 256, 0, stream>>>(
                OFFc, ATTc, V[0], V[1], V[2], V[3], Tq, row0);
            gemm_f<<<dim3(mcg, 4), 256, 0, stream>>>(
                Tq, Wo_l, bo_l, X + (size_t)row0 * D_, PRE, mc, 256, 256, 256, 256, 0);
            ln_kernel<<<(mc + 3) / 4, 256, 0, stream>>>(PRE, g1_l, b1_l, X, row0, mc);
        }

        // FFN, chunked (H1 overlays Tq/OFF/ATT; PRE disjoint)
        for (int c = 0; c < NC; ++c) {
            int row0 = c * RC;
            int mc = MROWS - row0; if (mc > RC) mc = RC;
            if (mc <= 0) break;
            int mcg = (mc + 63) / 64;
            float* Xc = X + (size_t)row0 * D_;
            gemm_f<<<dim3(mcg, 16), 256, 0, stream>>>(
                Xc, W1_l, bb1_l, nullptr, H1, mc, 1024, 256, 1024, 1024, 1);
            gemm_f<<<dim3(mcg, 4), 256, 0, stream>>>(
                H1, W2_l, bb2_l, Xc, PRE, mc, 256, 1024, 256, 256, 0);
            ln_kernel<<<(mc + 3) / 4, 256, 0, stream>>>(PRE, g2_l, b2_l, X, row0, mc);
        }
    }
}

// Round 11
// 4194.841 us; speedup vs baseline: 1.8049x; 1.8049x over previous
//
#include <hip/hip_runtime.h>
#include <math.h>

#define Q_ 13294
#define D_ 256
#define NLAYERS_ 6
#define MROWS 26588
#define MD ((size_t)MROWS * D_)

typedef unsigned short ushort_t;
typedef short bf16x8 __attribute__((ext_vector_type(8)));
typedef float f32x4 __attribute__((ext_vector_type(4)));
typedef ushort_t u16x8 __attribute__((ext_vector_type(8)));

__device__ __forceinline__ float u2f(ushort_t u) {
    return __uint_as_float(((unsigned)u) << 16);
}
__device__ __forceinline__ ushort_t f2bf(float f) {
    unsigned u = __float_as_uint(f);
    return (ushort_t)((u + 0x7fffu + ((u >> 16) & 1u)) >> 16);
}
__device__ __forceinline__ void decode_row(int gr, int& b, int& l, int& p) {
    b = (gr >= Q_) ? 1 : 0;
    int q = gr - b * Q_;
    if (q < 10000)      { l = 0; p = q; }
    else if (q < 12500) { l = 1; p = q - 10000; }
    else if (q < 13125) { l = 2; p = q - 12500; }
    else                { l = 3; p = q - 13125; }
}

// ---------------------------------------------------------------------------
// Flatten src (fp32 transpose): X[b, s_l+p, d] = src_l[b,d,p]
// grid (313, 8, 8), block (32,8)
// ---------------------------------------------------------------------------
__global__ __launch_bounds__(256)
void flatten_kernel(const float* __restrict__ s0, const float* __restrict__ s1,
                    const float* __restrict__ s2, const float* __restrict__ s3,
                    float* __restrict__ X)
{
    const int lHW[4] = {10000, 2500, 625, 169};
    const int lS[4]  = {0, 10000, 12500, 13125};
    int z = blockIdx.z;
    int l = z & 3, b = z >> 2;
    int HW = lHW[l];
    int p0 = blockIdx.x * 32;
    if (p0 >= HW) return;
    int d0 = blockIdx.y * 32;
    const float* src = (l == 0) ? s0 : (l == 1) ? s1 : (l == 2) ? s2 : s3;
    int tx = threadIdx.x, ty = threadIdx.y;
    __shared__ float t[32][33];
    #pragma unroll
    for (int i = 0; i < 4; ++i) {
        int d = d0 + ty + 8 * i, p = p0 + tx;
        t[ty + 8 * i][tx] = (p < HW) ? src[(size_t)(b * D_ + d) * HW + p] : 0.f;
    }
    __syncthreads();
    #pragma unroll
    for (int i = 0; i < 4; ++i) {
        int p = p0 + ty + 8 * i, d = d0 + tx;
        if (p < HW)
            X[(size_t)(b * Q_ + lS[l] + p) * D_ + d] = t[tx][ty + 8 * i];
    }
}

// ---------------------------------------------------------------------------
// Weight transpose+convert for one layer: Wt[n][k](bf16) = W[k][n](fp32)
// grid (256, 6), block (32,8). y = matrix index.
// ---------------------------------------------------------------------------
__global__ __launch_bounds__(256)
void wconv_kernel(const float* __restrict__ Woff, const float* __restrict__ Wattn,
                  const float* __restrict__ Wv, const float* __restrict__ Wo,
                  const float* __restrict__ W1, const float* __restrict__ W2,
                  ushort_t* __restrict__ WBl)
{
    const int mk[6] = {256, 256, 256, 256, 256, 1024};
    const int mn[6] = {256, 128, 256, 256, 1024, 256};
    const int mo[6] = {0, 65536, 98304, 163840, 229376, 491520};
    int m = blockIdx.y;
    int K = mk[m], N = mn[m];
    int tilesN = N >> 5;
    int tiles = (K >> 5) * tilesN;
    int tid = blockIdx.x;
    if (tid >= tiles) return;
    int tk = tid / tilesN, tn = tid - tk * tilesN;
    const float* Wsrc = (m == 0) ? Woff : (m == 1) ? Wattn : (m == 2) ? Wv :
                        (m == 3) ? Wo : (m == 4) ? W1 : W2;
    ushort_t* dst = WBl + mo[m];
    __shared__ float t[32][33];
    int tx = threadIdx.x, ty = threadIdx.y;
    #pragma unroll
    for (int i = 0; i < 4; ++i) {
        int k = tk * 32 + ty + 8 * i, n = tn * 32 + tx;
        t[ty + 8 * i][tx] = Wsrc[(size_t)k * N + n];
    }
    __syncthreads();
    #pragma unroll
    for (int i = 0; i < 4; ++i) {
        int n = tn * 32 + ty + 8 * i, k = tk * 32 + tx;
        dst[(size_t)n * K + k] = f2bf(t[tx][ty + 8 * i]);
    }
}

// ---------------------------------------------------------------------------
// qmake: Tq[r, d] (bf16) = X[row0+r, d] + pos_l[b, d, p] + level_embed[l, d]
// 64 threads per row, 4 d's per thread.
// ---------------------------------------------------------------------------
__global__ __launch_bounds__(256)
void qmake_kernel(const float* __restrict__ X,
                  const float* __restrict__ p0_, const float* __restrict__ p1_,
                  const float* __restrict__ p2_, const float* __restrict__ p3_,
                  const float* __restrict__ le,
                  ushort_t* __restrict__ Tq, int row0, int mc)
{
    const int lHW[4] = {10000, 2500, 625, 169};
    int gid = blockIdx.x * 256 + threadIdx.x;
    int r = gid >> 6, d4 = gid & 63;
    if (r >= mc) return;
    int gr = row0 + r;
    int b, l, p;
    decode_row(gr, b, l, p);
    const float* pos = (l == 0) ? p0_ : (l == 1) ? p1_ : (l == 2) ? p2_ : p3_;
    int HW = lHW[l];
    int d = d4 * 4;
    float4 xv = *(const float4*)(X + (size_t)gr * D_ + d);
    ushort4 o;
    o.x = f2bf(xv.x + pos[(size_t)(b * D_ + d + 0) * HW + p] + le[l * D_ + d + 0]);
    o.y = f2bf(xv.y + pos[(size_t)(b * D_ + d + 1) * HW + p] + le[l * D_ + d + 1]);
    o.z = f2bf(xv.z + pos[(size_t)(b * D_ + d + 2) * HW + p] + le[l * D_ + d + 2]);
    o.w = f2bf(xv.w + pos[(size_t)(b * D_ + d + 3) * HW + p] + le[l * D_ + d + 3]);
    *(ushort4*)(Tq + (size_t)r * D_ + d) = o;
}

// ---------------------------------------------------------------------------
// MFMA bf16 GEMM: C[M,N](ldc) = A[M,K] @ Wt^T + bias  (Wt is [N][K] bf16)
// AF=1: A fp32 (converted in staging); AF=0: A bf16.
// CB=1: C bf16; CB=0: C fp32.  Optional fp32 residual Rres (ldc), relu.
// Tile 128x64, BK=64, 256 thr = 4 waves in 2x2, v_mfma_f32_16x16x32_bf16.
// Layouts (verified, learn_hip m89/m91): A-frag lane: m=lane&15, k=quad*8+j;
// B-frag lane: n=lane&15, k=quad*8+j; C/D: col=lane&15, row=quad*4+reg.
// ---------------------------------------------------------------------------
template<int AF, int CB>
__global__ __launch_bounds__(256)
void gemm_m(const void* __restrict__ Ap, const ushort_t* __restrict__ Wt,
            const float* __restrict__ bias, const float* __restrict__ Rres,
            void* __restrict__ Cp, int M, int K, int ldc, int relu)
{
    __shared__ ushort_t Asm[128][72];
    __shared__ ushort_t Bsm[64][72];
    int t = threadIdx.x;
    int m0 = blockIdx.x * 128, n0 = blockIdx.y * 64;
    int w = t >> 6, lane = t & 63;
    int wm = (w & 1) * 64, wn = (w >> 1) * 32;
    int lm = lane & 15, quad = lane >> 4;
    f32x4 acc[4][2] = {};

    for (int k0 = 0; k0 < K; k0 += 64) {
        if (AF) {
            const float* A = (const float*)Ap;
            int ar = t >> 4, ac = t & 15;
            #pragma unroll
            for (int i = 0; i < 8; ++i) {
                int row = ar + 16 * i;
                int gr = m0 + row;
                float4 av = make_float4(0.f, 0.f, 0.f, 0.f);
                if (gr < M) av = *(const float4*)(A + (size_t)gr * K + k0 + ac * 4);
                ushort4 u;
                u.x = f2bf(av.x); u.y = f2bf(av.y); u.z = f2bf(av.z); u.w = f2bf(av.w);
                *(ushort4*)&Asm[row][ac * 4] = u;
            }
        } else {
            const ushort_t* A = (const ushort_t*)Ap;
            int ar = t >> 3, ac = t & 7;
            #pragma unroll
            for (int i = 0; i < 4; ++i) {
                int row = ar + 32 * i;
                int gr = m0 + row;
                u16x8 av = {};
                if (gr < M) av = *(const u16x8*)(A + (size_t)gr * K + k0 + ac * 8);
                *(u16x8*)&Asm[row][ac * 8] = av;
            }
        }
        {
            int br = t >> 3, bc = t & 7;
            #pragma unroll
            for (int i = 0; i < 2; ++i) {
                int n = br + 32 * i;
                u16x8 bv = *(const u16x8*)(Wt + (size_t)(n0 + n) * K + k0 + bc * 8);
                *(u16x8*)&Bsm[n][bc * 8] = bv;
            }
        }
        __syncthreads();
        #pragma unroll
        for (int ks = 0; ks < 64; ks += 32) {
            bf16x8 af[4], bfr[2];
            #pragma unroll
            for (int i = 0; i < 4; ++i)
                af[i] = *(const bf16x8*)&Asm[wm + i * 16 + lm][ks + quad * 8];
            #pragma unroll
            for (int j = 0; j < 2; ++j)
                bfr[j] = *(const bf16x8*)&Bsm[wn + j * 16 + lm][ks + quad * 8];
            #pragma unroll
            for (int i = 0; i < 4; ++i)
                #pragma unroll
                for (int j = 0; j < 2; ++j)
                    acc[i][j] = __builtin_amdgcn_mfma_f32_16x16x32_bf16(
                        af[i], bfr[j], acc[i][j], 0, 0, 0);
        }
        __syncthreads();
    }

    #pragma unroll
    for (int i = 0; i < 4; ++i) {
        #pragma unroll
        for (int j = 0; j < 2; ++j) {
            int col = n0 + wn + j * 16 + lm;
            float bc = bias[col];
            #pragma unroll
            for (int r = 0; r < 4; ++r) {
                int row = m0 + wm + i * 16 + quad * 4 + r;
                if (row >= M) continue;
                float v = acc[i][j][r] + bc;
                if (Rres) v += Rres[(size_t)row * ldc + col];
                if (relu) v = fmaxf(v, 0.f);
                if (CB) ((ushort_t*)Cp)[(size_t)row * ldc + col] = f2bf(v);
                else    ((float*)Cp)[(size_t)row * ldc + col] = v;
            }
        }
    }
}

// ---------------------------------------------------------------------------
// LayerNorm chunk: X[row0+r] = LN(PRE[r]) * g + b (fp32). one wave per row.
// ---------------------------------------------------------------------------
__global__ __launch_bounds__(256)
void ln_kernel(const float* __restrict__ P, const float* __restrict__ g,
               const float* __restrict__ b, float* __restrict__ Xo,
               int row0, int mc)
{
    int wave = threadIdx.x >> 6, lane = threadIdx.x & 63;
    int r = blockIdx.x * 4 + wave;
    if (r >= mc) return;
    const float* x = P + (size_t)r * D_;
    float4 v = *(const float4*)(x + lane * 4);
    float s = v.x + v.y + v.z + v.w;
    float sq = v.x * v.x + v.y * v.y + v.z * v.z + v.w * v.w;
    #pragma unroll
    for (int o = 32; o > 0; o >>= 1) {
        s += __shfl_xor(s, o, 64);
        sq += __shfl_xor(sq, o, 64);
    }
    float mean = s * (1.f / 256.f);
    float var = fmaxf(sq * (1.f / 256.f) - mean * mean, 0.f);
    float rs = rsqrtf(var + 1e-5f);
    float4 gv = *(const float4*)(g + lane * 4);
    float4 bv = *(const float4*)(b + lane * 4);
    float4 o;
    o.x = (v.x - mean) * rs * gv.x + bv.x;
    o.y = (v.y - mean) * rs * gv.y + bv.y;
    o.z = (v.z - mean) * rs * gv.z + bv.z;
    o.w = (v.w - mean) * rs * gv.w + bv.w;
    *(float4*)(Xo + (size_t)(row0 + r) * D_ + lane * 4) = o;
}

// ---------------------------------------------------------------------------
// Deformable sampling: softmax(16 logits, fp32) + 16-pt bilinear gather from
// bf16 VAL, branchless clip+valid. Output SAMP bf16.
// block = one row; 256 threads = 8 heads x 32 hd.
// ---------------------------------------------------------------------------
__global__ __launch_bounds__(256)
void sample_kernel(const float* __restrict__ OFF, const float* __restrict__ ATT,
                   const ushort_t* __restrict__ V0, const ushort_t* __restrict__ V1,
                   const ushort_t* __restrict__ V2, const ushort_t* __restrict__ V3,
                   ushort_t* __restrict__ OUT, int row0)
{
    const int lH[4]  = {100, 50, 25, 13};
    const int lW[4]  = {100, 50, 25, 13};
    const int lHW[4] = {10000, 2500, 625, 169};

    int r = blockIdx.x;
    int gr = row0 + r;
    int b, lq, p;
    decode_row(gr, b, lq, p);
    int h = threadIdx.x >> 5, hd = threadIdx.x & 31;

    int rw = lW[lq];
    int prow = p / rw, pcol = p - prow * rw;
    float refx = (pcol + 0.5f) / (float)lW[lq];
    float refy = (prow + 0.5f) / (float)lH[lq];

    const float* offp = OFF + (size_t)r * 256 + h * 32;
    const float* attp = ATT + (size_t)r * 128 + h * 16;

    float w16[16];
    float mx = -1e30f;
    #pragma unroll
    for (int j = 0; j < 16; ++j) { w16[j] = attp[j]; mx = fmaxf(mx, w16[j]); }
    float ssum = 0.f;
    #pragma unroll
    for (int j = 0; j < 16; ++j) { w16[j] = __expf(w16[j] - mx); ssum += w16[j]; }
    float inv = 1.f / ssum;

    float o = 0.f;
    #pragma unroll
    for (int l = 0; l < 4; ++l) {
        int Wl = lW[l], Hl = lH[l];
        const ushort_t* vl = ((l == 0) ? V0 : (l == 1) ? V1 : (l == 2) ? V2 : V3)
                             + ((size_t)b * lHW[l]) * D_ + h * 32 + hd;
        #pragma unroll
        for (int pp = 0; pp < 4; ++pp) {
            float ox = offp[l * 8 + pp * 2 + 0];
            float oy = offp[l * 8 + pp * 2 + 1];
            float xf = (refx + ox / (float)Wl) * Wl - 0.5f;
            float yf = (refy + oy / (float)Hl) * Hl - 0.5f;
            xf = fmaxf(fminf(xf, 1.0e6f), -1.0e6f);
            yf = fmaxf(fminf(yf, 1.0e6f), -1.0e6f);
            float x0f = floorf(xf), y0f = floorf(yf);
            float fx = xf - x0f, fy = yf - y0f;
            int x0 = (int)x0f, y0 = (int)y0f;
            int x1 = x0 + 1, y1 = y0 + 1;
            int x0c = min(max(x0, 0), Wl - 1), x1c = min(max(x1, 0), Wl - 1);
            int y0c = min(max(y0, 0), Hl - 1), y1c = min(max(y1, 0), Hl - 1);
            float vx0 = (x0 >= 0 && x0 < Wl) ? 1.f : 0.f;
            float vx1 = (x1 >= 0 && x1 < Wl) ? 1.f : 0.f;
            float vy0 = (y0 >= 0 && y0 < Hl) ? 1.f : 0.f;
            float vy1 = (y1 >= 0 && y1 < Hl) ? 1.f : 0.f;
            float g00 = u2f(vl[(size_t)(y0c * Wl + x0c) * D_]);
            float g10 = u2f(vl[(size_t)(y0c * Wl + x1c) * D_]);
            float g01 = u2f(vl[(size_t)(y1c * Wl + x0c) * D_]);
            float g11 = u2f(vl[(size_t)(y1c * Wl + x1c) * D_]);
            float accv = (1.f - fx) * (1.f - fy) * vx0 * vy0 * g00
                       + fx * (1.f - fy) * vx1 * vy0 * g10
                       + (1.f - fx) * fy * vx0 * vy1 * g01
                       + fx * fy * vx1 * vy1 * g11;
            o += w16[l * 4 + pp] * inv * accv;
        }
    }
    OUT[(size_t)r * D_ + h * 32 + hd] = f2bf(o);
}

extern "C" void kernel_launch(void* const* d_in, const int* in_sizes, int n_in,
                              void* d_out, int out_size, void* d_ws, size_t ws_size,
                              hipStream_t stream)
{
    // setup_inputs() dict order interleaves src/pos (sizes pair up).
    bool interleaved = (in_sizes[0] == in_sizes[1]);
    int si[4], pi[4];
    for (int i = 0; i < 4; ++i) {
        si[i] = interleaved ? 2 * i : i;
        pi[i] = interleaved ? 2 * i + 1 : 4 + i;
    }
    const float* src0 = (const float*)d_in[si[0]];
    const float* src1 = (const float*)d_in[si[1]];
    const float* src2 = (const float*)d_in[si[2]];
    const float* src3 = (const float*)d_in[si[3]];
    const float* pos0 = (const float*)d_in[pi[0]];
    const float* pos1 = (const float*)d_in[pi[1]];
    const float* pos2 = (const float*)d_in[pi[2]];
    const float* pos3 = (const float*)d_in[pi[3]];
    const float* level_embed = (const float*)d_in[8];
    const float* Woff  = (const float*)d_in[9];
    const float* boff  = (const float*)d_in[10];
    const float* Wattn = (const float*)d_in[11];
    const float* battn = (const float*)d_in[12];
    const float* Wv = (const float*)d_in[13];
    const float* bv = (const float*)d_in[14];
    const float* Wo = (const float*)d_in[15];
    const float* bo = (const float*)d_in[16];
    const float* g1 = (const float*)d_in[17];
    const float* b1 = (const float*)d_in[18];
    const float* W1  = (const float*)d_in[19];
    const float* bb1 = (const float*)d_in[20];
    const float* W2  = (const float*)d_in[21];
    const float* bb2 = (const float*)d_in[22];
    const float* g2 = (const float*)d_in[23];
    const float* b2 = (const float*)d_in[24];

    // VAL (bf16) lives in the consumed-after-flatten src input buffers
    // (half their fp32 byte size). Harness restores inputs before every launch.
    ushort_t* V[4] = { (ushort_t*)d_in[si[0]], (ushort_t*)d_in[si[1]],
                       (ushort_t*)d_in[si[2]], (ushort_t*)d_in[si[3]] };

    // X (fp32 state) lives in d_out; the final LN writes the output in place.
    float* X = (float*)d_out;

    const int lHW[4] = {10000, 2500, 625, 169};
    const int lS[4]  = {0, 10000, 12500, 13125};
    // per-layer bf16 transposed-weight block: 753,664 elems
    const int WOFF_T = 0, WATT_T = 65536, WV_T = 98304, WO_T = 163840,
              W1_T = 229376, W2_T = 491520;
    const size_t WB_ELEMS = 753664;

    // ws = WB (1.507 MB) + chunk region R = RC*3072 bytes:
    //   Tqu bf16 [RC,256] @0 | OFF f32 [RC,256] @RC*512 | ATT f32 [RC,128]
    //   @RC*1536 | PRE f32 [RC,256] @RC*2048.  FFN: H1u bf16 [RC,1024] @0.
    const int cand[9] = {1, 2, 4, 8, 16, 32, 64, 128, 256};
    int NC = 256;
    for (int i = 0; i < 9; ++i) {
        int rc = (MROWS + cand[i] - 1) / cand[i];
        size_t need = WB_ELEMS * 2 + (size_t)rc * 3072 + 1024;
        if (need <= ws_size) { NC = cand[i]; break; }
    }
    const int RC = (MROWS + NC - 1) / NC;

    ushort_t* WBl  = (ushort_t*)d_ws;
    char* Rbase    = (char*)d_ws + WB_ELEMS * 2;
    ushort_t* Tqu  = (ushort_t*)Rbase;
    float* OFFc    = (float*)(Rbase + (size_t)RC * 512);
    float* ATTc    = (float*)(Rbase + (size_t)RC * 1536);
    float* PRE     = (float*)(Rbase + (size_t)RC * 2048);
    ushort_t* H1u  = (ushort_t*)Rbase;

    flatten_kernel<<<dim3(313, 8, 8), dim3(32, 8), 0, stream>>>(src0, src1, src2, src3, X);

    for (int l = 0; l < NLAYERS_; ++l) {
        const float* Woff_l  = Woff  + (size_t)l * D_ * 256;
        const float* boff_l  = boff  + (size_t)l * 256;
        const float* Wattn_l = Wattn + (size_t)l * D_ * 128;
        const float* battn_l = battn + (size_t)l * 128;
        const float* Wv_l = Wv + (size_t)l * D_ * D_;
        const float* bv_l = bv + (size_t)l * D_;
        const float* Wo_l = Wo + (size_t)l * D_ * D_;
        const float* bo_l = bo + (size_t)l * D_;
        const float* g1_l = g1 + (size_t)l * D_;
        const float* b1_l = b1 + (size_t)l * D_;
        const float* W1_l  = W1  + (size_t)l * D_ * 1024;
        const float* bb1_l = bb1 + (size_t)l * 1024;
        const float* W2_l  = W2  + (size_t)l * 1024 * D_;
        const float* bb2_l = bb2 + (size_t)l * D_;
        const float* g2_l = g2 + (size_t)l * D_;
        const float* b2_l = b2 + (size_t)l * D_;

        // transpose+convert this layer's weights to bf16 [N][K]
        wconv_kernel<<<dim3(256, 6), dim3(32, 8), 0, stream>>>(
            Woff_l, Wattn_l, Wv_l, Wo_l, W1_l, W2_l, WBl);

        // VAL = X @ Wv + bv (bf16, per level/batch into src buffers)
        for (int lv = 0; lv < 4; ++lv) {
            for (int bb = 0; bb < 2; ++bb) {
                int Ml = lHW[lv];
                gemm_m<1, 1><<<dim3((Ml + 127) / 128, 4), 256, 0, stream>>>(
                    X + (size_t)(bb * Q_ + lS[lv]) * D_, WBl + WV_T, bv_l,
                    nullptr, V[lv] + (size_t)bb * lHW[lv] * D_, Ml, 256, 256, 0);
            }
        }

        // attention, chunked
        for (int c = 0; c < NC; ++c) {
            int row0 = c * RC;
            int mc = MROWS - row0; if (mc > RC) mc = RC;
            if (mc <= 0) break;
            int mg = (mc + 127) / 128;
            qmake_kernel<<<(mc * 64 + 255) / 256, 256, 0, stream>>>(
                X, pos0, pos1, pos2, pos3, level_embed, Tqu, row0, mc);
            gemm_m<0, 0><<<dim3(mg, 4), 256, 0, stream>>>(
                Tqu, WBl + WOFF_T, boff_l, nullptr, OFFc, mc, 256, 256, 0);
            gemm_m<0, 0><<<dim3(mg, 2), 256, 0, stream>>>(
                Tqu, WBl + WATT_T, battn_l, nullptr, ATTc, mc, 256, 128, 0);
            sample_kernel<<<mc, 256, 0, stream>>>(
                OFFc, ATTc, V[0], V[1], V[2], V[3], Tqu, row0);
            gemm_m<0, 0><<<dim3(mg, 4), 256, 0, stream>>>(
                Tqu, WBl + WO_T, bo_l, X + (size_t)row0 * D_, PRE, mc, 256, 256, 0);
            ln_kernel<<<(mc + 3) / 4, 256, 0, stream>>>(PRE, g1_l, b1_l, X, row0, mc);
        }

        // FFN, chunked (H1u overlays Tqu/OFF/ATT; PRE disjoint)
        for (int c = 0; c < NC; ++c) {
            int row0 = c * RC;
            int mc = MROWS - row0; if (mc > RC) mc = RC;
            if (mc <= 0) break;
            int mg = (mc + 127) / 128;
            float* Xc = X + (size_t)row0 * D_;
            gemm_m<1, 1><<<dim3(mg, 16), 256, 0, stream>>>(
                Xc, WBl + W1_T, bb1_l, nullptr, H1u, mc, 256, 1024, 1);
            gemm_m<0, 0><<<dim3(mg, 4), 256, 0, stream>>>(
                H1u, WBl + W2_T, bb2_l, Xc, PRE, mc, 1024, 256, 0);
            ln_kernel<<<(mc + 3) / 4, 256, 0, stream>>>(PRE, g2_l, b2_l, X, row0, mc);
        }
    }
}

// Round 12
// 2863.534 us; speedup vs baseline: 2.6440x; 1.4649x over previous
//
#include <hip/hip_runtime.h>
#include <math.h>

#define Q_ 13294
#define D_ 256
#define NLAYERS_ 6
#define MROWS 26588
#define MD ((size_t)MROWS * D_)

typedef unsigned short ushort_t;
typedef short bf16x8 __attribute__((ext_vector_type(8)));
typedef float f32x4 __attribute__((ext_vector_type(4)));
typedef ushort_t u16x8 __attribute__((ext_vector_type(8)));

__device__ __forceinline__ float u2f(ushort_t u) {
    return __uint_as_float(((unsigned)u) << 16);
}
__device__ __forceinline__ ushort_t f2bf(float f) {
    unsigned u = __float_as_uint(f);
    return (ushort_t)((u + 0x7fffu + ((u >> 16) & 1u)) >> 16);
}
__device__ __forceinline__ void decode_row(int gr, int& b, int& l, int& p) {
    b = (gr >= Q_) ? 1 : 0;
    int q = gr - b * Q_;
    if (q < 10000)      { l = 0; p = q; }
    else if (q < 12500) { l = 1; p = q - 10000; }
    else if (q < 13125) { l = 2; p = q - 12500; }
    else                { l = 3; p = q - 13125; }
}

// ---------------------------------------------------------------------------
// Flatten src (fp32 transpose): X[b, s_l+p, d] = src_l[b,d,p]
// grid (313, 8, 8), block (32,8)
// ---------------------------------------------------------------------------
__global__ __launch_bounds__(256)
void flatten_kernel(const float* __restrict__ s0, const float* __restrict__ s1,
                    const float* __restrict__ s2, const float* __restrict__ s3,
                    float* __restrict__ X)
{
    const int lHW[4] = {10000, 2500, 625, 169};
    const int lS[4]  = {0, 10000, 12500, 13125};
    int z = blockIdx.z;
    int l = z & 3, b = z >> 2;
    int HW = lHW[l];
    int p0 = blockIdx.x * 32;
    if (p0 >= HW) return;
    int d0 = blockIdx.y * 32;
    const float* src = (l == 0) ? s0 : (l == 1) ? s1 : (l == 2) ? s2 : s3;
    int tx = threadIdx.x, ty = threadIdx.y;
    __shared__ float t[32][33];
    #pragma unroll
    for (int i = 0; i < 4; ++i) {
        int d = d0 + ty + 8 * i, p = p0 + tx;
        t[ty + 8 * i][tx] = (p < HW) ? src[(size_t)(b * D_ + d) * HW + p] : 0.f;
    }
    __syncthreads();
    #pragma unroll
    for (int i = 0; i < 4; ++i) {
        int p = p0 + ty + 8 * i, d = d0 + tx;
        if (p < HW)
            X[(size_t)(b * Q_ + lS[l] + p) * D_ + d] = t[tx][ty + 8 * i];
    }
}

// ---------------------------------------------------------------------------
// Weight transpose+convert for one layer: Wt[n][k](bf16) = W[k][n](fp32)
// grid (256, 6), block (32,8). y = matrix index.
// ---------------------------------------------------------------------------
__global__ __launch_bounds__(256)
void wconv_kernel(const float* __restrict__ Woff, const float* __restrict__ Wattn,
                  const float* __restrict__ Wv, const float* __restrict__ Wo,
                  const float* __restrict__ W1, const float* __restrict__ W2,
                  ushort_t* __restrict__ WBl)
{
    const int mk[6] = {256, 256, 256, 256, 256, 1024};
    const int mn[6] = {256, 128, 256, 256, 1024, 256};
    const int mo[6] = {0, 65536, 98304, 163840, 229376, 491520};
    int m = blockIdx.y;
    int K = mk[m], N = mn[m];
    int tilesN = N >> 5;
    int tiles = (K >> 5) * tilesN;
    int tid = blockIdx.x;
    if (tid >= tiles) return;
    int tk = tid / tilesN, tn = tid - tk * tilesN;
    const float* Wsrc = (m == 0) ? Woff : (m == 1) ? Wattn : (m == 2) ? Wv :
                        (m == 3) ? Wo : (m == 4) ? W1 : W2;
    ushort_t* dst = WBl + mo[m];
    __shared__ float t[32][33];
    int tx = threadIdx.x, ty = threadIdx.y;
    #pragma unroll
    for (int i = 0; i < 4; ++i) {
        int k = tk * 32 + ty + 8 * i, n = tn * 32 + tx;
        t[ty + 8 * i][tx] = Wsrc[(size_t)k * N + n];
    }
    __syncthreads();
    #pragma unroll
    for (int i = 0; i < 4; ++i) {
        int n = tn * 32 + ty + 8 * i, k = tk * 32 + tx;
        dst[(size_t)n * K + k] = f2bf(t[tx][ty + 8 * i]);
    }
}

// ---------------------------------------------------------------------------
// qmake: Tq[r, d] (bf16) = X[row0+r, d] + pos_l[b, d, p] + level_embed[l, d]
// 64 threads per row, 4 d's per thread.
// ---------------------------------------------------------------------------
__global__ __launch_bounds__(256)
void qmake_kernel(const float* __restrict__ X,
                  const float* __restrict__ p0_, const float* __restrict__ p1_,
                  const float* __restrict__ p2_, const float* __restrict__ p3_,
                  const float* __restrict__ le,
                  ushort_t* __restrict__ Tq, int row0, int mc)
{
    const int lHW[4] = {10000, 2500, 625, 169};
    int gid = blockIdx.x * 256 + threadIdx.x;
    int r = gid >> 6, d4 = gid & 63;
    if (r >= mc) return;
    int gr = row0 + r;
    int b, l, p;
    decode_row(gr, b, l, p);
    const float* pos = (l == 0) ? p0_ : (l == 1) ? p1_ : (l == 2) ? p2_ : p3_;
    int HW = lHW[l];
    int d = d4 * 4;
    float4 xv = *(const float4*)(X + (size_t)gr * D_ + d);
    ushort4 o;
    o.x = f2bf(xv.x + pos[(size_t)(b * D_ + d + 0) * HW + p] + le[l * D_ + d + 0]);
    o.y = f2bf(xv.y + pos[(size_t)(b * D_ + d + 1) * HW + p] + le[l * D_ + d + 1]);
    o.z = f2bf(xv.z + pos[(size_t)(b * D_ + d + 2) * HW + p] + le[l * D_ + d + 2]);
    o.w = f2bf(xv.w + pos[(size_t)(b * D_ + d + 3) * HW + p] + le[l * D_ + d + 3]);
    *(ushort4*)(Tq + (size_t)r * D_ + d) = o;
}

// ---------------------------------------------------------------------------
// MFMA bf16 GEMM: C[M,N](ldc) = A[M,K] @ Wt^T + bias  (Wt is [N][K] bf16)
// AF=1: A fp32 (converted in staging); AF=0: A bf16.
// CB=1: C bf16; CB=0: C fp32.  Optional fp32 residual Rres (ldc), relu.
// Tile 128x64, BK=64, 256 thr = 4 waves in 2x2, v_mfma_f32_16x16x32_bf16.
// ---------------------------------------------------------------------------
template<int AF, int CB>
__global__ __launch_bounds__(256)
void gemm_m(const void* __restrict__ Ap, const ushort_t* __restrict__ Wt,
            const float* __restrict__ bias, const float* __restrict__ Rres,
            void* __restrict__ Cp, int M, int K, int ldc, int relu)
{
    __shared__ ushort_t Asm[128][72];
    __shared__ ushort_t Bsm[64][72];
    int t = threadIdx.x;
    int m0 = blockIdx.x * 128, n0 = blockIdx.y * 64;
    int w = t >> 6, lane = t & 63;
    int wm = (w & 1) * 64, wn = (w >> 1) * 32;
    int lm = lane & 15, quad = lane >> 4;
    f32x4 acc[4][2] = {};

    for (int k0 = 0; k0 < K; k0 += 64) {
        if (AF) {
            const float* A = (const float*)Ap;
            int ar = t >> 4, ac = t & 15;
            #pragma unroll
            for (int i = 0; i < 8; ++i) {
                int row = ar + 16 * i;
                int gr = m0 + row;
                float4 av = make_float4(0.f, 0.f, 0.f, 0.f);
                if (gr < M) av = *(const float4*)(A + (size_t)gr * K + k0 + ac * 4);
                ushort4 u;
                u.x = f2bf(av.x); u.y = f2bf(av.y); u.z = f2bf(av.z); u.w = f2bf(av.w);
                *(ushort4*)&Asm[row][ac * 4] = u;
            }
        } else {
            const ushort_t* A = (const ushort_t*)Ap;
            int ar = t >> 3, ac = t & 7;
            #pragma unroll
            for (int i = 0; i < 4; ++i) {
                int row = ar + 32 * i;
                int gr = m0 + row;
                u16x8 av = {};
                if (gr < M) av = *(const u16x8*)(A + (size_t)gr * K + k0 + ac * 8);
                *(u16x8*)&Asm[row][ac * 8] = av;
            }
        }
        {
            int br = t >> 3, bc = t & 7;
            #pragma unroll
            for (int i = 0; i < 2; ++i) {
                int n = br + 32 * i;
                u16x8 bv = *(const u16x8*)(Wt + (size_t)(n0 + n) * K + k0 + bc * 8);
                *(u16x8*)&Bsm[n][bc * 8] = bv;
            }
        }
        __syncthreads();
        #pragma unroll
        for (int ks = 0; ks < 64; ks += 32) {
            bf16x8 af[4], bfr[2];
            #pragma unroll
            for (int i = 0; i < 4; ++i)
                af[i] = *(const bf16x8*)&Asm[wm + i * 16 + lm][ks + quad * 8];
            #pragma unroll
            for (int j = 0; j < 2; ++j)
                bfr[j] = *(const bf16x8*)&Bsm[wn + j * 16 + lm][ks + quad * 8];
            #pragma unroll
            for (int i = 0; i < 4; ++i)
                #pragma unroll
                for (int j = 0; j < 2; ++j)
                    acc[i][j] = __builtin_amdgcn_mfma_f32_16x16x32_bf16(
                        af[i], bfr[j], acc[i][j], 0, 0, 0);
        }
        __syncthreads();
    }

    #pragma unroll
    for (int i = 0; i < 4; ++i) {
        #pragma unroll
        for (int j = 0; j < 2; ++j) {
            int col = n0 + wn + j * 16 + lm;
            float bc = bias[col];
            #pragma unroll
            for (int r = 0; r < 4; ++r) {
                int row = m0 + wm + i * 16 + quad * 4 + r;
                if (row >= M) continue;
                float v = acc[i][j][r] + bc;
                if (Rres) v += Rres[(size_t)row * ldc + col];
                if (relu) v = fmaxf(v, 0.f);
                if (CB) ((ushort_t*)Cp)[(size_t)row * ldc + col] = f2bf(v);
                else    ((float*)Cp)[(size_t)row * ldc + col] = v;
            }
        }
    }
}

// ---------------------------------------------------------------------------
// LayerNorm chunk: X[row0+r] = LN(PRE[r]) * g + b (fp32). one wave per row.
// ---------------------------------------------------------------------------
__global__ __launch_bounds__(256)
void ln_kernel(const float* __restrict__ P, const float* __restrict__ g,
               const float* __restrict__ b, float* __restrict__ Xo,
               int row0, int mc)
{
    int wave = threadIdx.x >> 6, lane = threadIdx.x & 63;
    int r = blockIdx.x * 4 + wave;
    if (r >= mc) return;
    const float* x = P + (size_t)r * D_;
    float4 v = *(const float4*)(x + lane * 4);
    float s = v.x + v.y + v.z + v.w;
    float sq = v.x * v.x + v.y * v.y + v.z * v.z + v.w * v.w;
    #pragma unroll
    for (int o = 32; o > 0; o >>= 1) {
        s += __shfl_xor(s, o, 64);
        sq += __shfl_xor(sq, o, 64);
    }
    float mean = s * (1.f / 256.f);
    float var = fmaxf(sq * (1.f / 256.f) - mean * mean, 0.f);
    float rs = rsqrtf(var + 1e-5f);
    float4 gv = *(const float4*)(g + lane * 4);
    float4 bv = *(const float4*)(b + lane * 4);
    float4 o;
    o.x = (v.x - mean) * rs * gv.x + bv.x;
    o.y = (v.y - mean) * rs * gv.y + bv.y;
    o.z = (v.z - mean) * rs * gv.z + bv.z;
    o.w = (v.w - mean) * rs * gv.w + bv.w;
    *(float4*)(Xo + (size_t)(row0 + r) * D_ + lane * 4) = o;
}

// ---------------------------------------------------------------------------
// Deformable sampling, descriptor-staged. Block = 2 rows x 128 threads.
// Stage 1 (256 thr = 2 rows x 8 heads x 16 points): softmax over the 16
//   points of each head via 16-lane shfl reductions; bilinear corner pointers
//   + fused weights (attn * bilinear * valid) -> LDS descriptors.
// Stage 2 (2 rows x 8 heads x 16 lanes x 2 channels): per point, read the
//   broadcast descriptor, 4x u16x2 gathers, unpack (AND/SHL), FMA.
// ---------------------------------------------------------------------------
__global__ __launch_bounds__(256)
void sample_kernel(const float* __restrict__ OFF, const float* __restrict__ ATT,
                   const ushort_t* __restrict__ V0, const ushort_t* __restrict__ V1,
                   const ushort_t* __restrict__ V2, const ushort_t* __restrict__ V3,
                   ushort_t* __restrict__ OUT, int row0, int mc)
{
    const int lW[4]  = {100, 50, 25, 13};
    const int lH[4]  = {100, 50, 25, 13};
    const int lHW[4] = {10000, 2500, 625, 169};

    __shared__ const ushort_t* ptrs[256 * 4];
    __shared__ float wts[256 * 4];

    int tid = threadIdx.x;

    // ---- stage 1: descriptors ----
    {
        int r2 = tid >> 7;             // row within block
        int j  = tid & 127;            // head*16 + point
        int h  = j >> 4, pt = j & 15;
        int r  = blockIdx.x * 2 + r2;  // chunk-local row
        bool ok = (r < mc);
        int gr = row0 + (ok ? r : 0);
        int b, lq, p;
        decode_row(gr, b, lq, p);
        int rw = lW[lq];
        int prow = p / rw, pcol = p - prow * rw;
        float refx = (pcol + 0.5f) / (float)lW[lq];
        float refy = (prow + 0.5f) / (float)lH[lq];

        float logit = ok ? ATT[(size_t)r * 128 + h * 16 + pt] : 0.f;
        float mx = logit;
        #pragma unroll
        for (int o = 8; o > 0; o >>= 1) mx = fmaxf(mx, __shfl_xor(mx, o, 16));
        float e = __expf(logit - mx);
        float ssum = e;
        #pragma unroll
        for (int o = 8; o > 0; o >>= 1) ssum += __shfl_xor(ssum, o, 16);
        float a = e / ssum;

        int l = pt >> 2;
        int Wl = lW[l], Hl = lH[l];
        const ushort_t* base = ((l == 0) ? V0 : (l == 1) ? V1 : (l == 2) ? V2 : V3)
                               + ((size_t)b * lHW[l]) * D_ + h * 32;
        float ox = ok ? OFF[(size_t)r * 256 + h * 32 + pt * 2 + 0] : 0.f;
        float oy = ok ? OFF[(size_t)r * 256 + h * 32 + pt * 2 + 1] : 0.f;
        float xf = (refx + ox / (float)Wl) * Wl - 0.5f;
        float yf = (refy + oy / (float)Hl) * Hl - 0.5f;
        xf = fmaxf(fminf(xf, 1.0e6f), -1.0e6f);
        yf = fmaxf(fminf(yf, 1.0e6f), -1.0e6f);
        float x0f = floorf(xf), y0f = floorf(yf);
        float fx = xf - x0f, fy = yf - y0f;
        int x0 = (int)x0f, y0 = (int)y0f;
        int x1 = x0 + 1, y1 = y0 + 1;
        int x0c = min(max(x0, 0), Wl - 1), x1c = min(max(x1, 0), Wl - 1);
        int y0c = min(max(y0, 0), Hl - 1), y1c = min(max(y1, 0), Hl - 1);
        float vx0 = (x0 >= 0 && x0 < Wl) ? 1.f : 0.f;
        float vx1 = (x1 >= 0 && x1 < Wl) ? 1.f : 0.f;
        float vy0 = (y0 >= 0 && y0 < Hl) ? 1.f : 0.f;
        float vy1 = (y1 >= 0 && y1 < Hl) ? 1.f : 0.f;
        ptrs[tid * 4 + 0] = base + (size_t)(y0c * Wl + x0c) * D_;
        ptrs[tid * 4 + 1] = base + (size_t)(y0c * Wl + x1c) * D_;
        ptrs[tid * 4 + 2] = base + (size_t)(y1c * Wl + x0c) * D_;
        ptrs[tid * 4 + 3] = base + (size_t)(y1c * Wl + x1c) * D_;
        wts[tid * 4 + 0] = a * (1.f - fx) * (1.f - fy) * vx0 * vy0;
        wts[tid * 4 + 1] = a * fx * (1.f - fy) * vx1 * vy0;
        wts[tid * 4 + 2] = a * (1.f - fx) * fy * vx0 * vy1;
        wts[tid * 4 + 3] = a * fx * fy * vx1 * vy1;
    }
    __syncthreads();

    // ---- stage 2: gather ----
    int r2 = tid >> 7;
    int r  = blockIdx.x * 2 + r2;
    if (r >= mc) return;
    int h  = (tid >> 4) & 7;
    int ch = (tid & 15) * 2;           // 2 channels per thread
    int dbase = (r2 * 128 + h * 16) * 4;

    float o0 = 0.f, o1 = 0.f;
    #pragma unroll
    for (int pt = 0; pt < 16; ++pt) {
        int di = dbase + pt * 4;
        #pragma unroll
        for (int k = 0; k < 4; ++k) {
            float wk = wts[di + k];
            const ushort_t* pk = ptrs[di + k];
            unsigned v = *(const unsigned*)(pk + ch);
            float lo = __uint_as_float(v << 16);
            float hi = __uint_as_float(v & 0xffff0000u);
            o0 += wk * lo;
            o1 += wk * hi;
        }
    }
    unsigned pack = ((unsigned)f2bf(o1) << 16) | (unsigned)f2bf(o0);
    *(unsigned*)(OUT + (size_t)r * D_ + h * 32 + ch) = pack;
}

extern "C" void kernel_launch(void* const* d_in, const int* in_sizes, int n_in,
                              void* d_out, int out_size, void* d_ws, size_t ws_size,
                              hipStream_t stream)
{
    // setup_inputs() dict order interleaves src/pos (sizes pair up).
    bool interleaved = (in_sizes[0] == in_sizes[1]);
    int si[4], pi[4];
    for (int i = 0; i < 4; ++i) {
        si[i] = interleaved ? 2 * i : i;
        pi[i] = interleaved ? 2 * i + 1 : 4 + i;
    }
    const float* src0 = (const float*)d_in[si[0]];
    const float* src1 = (const float*)d_in[si[1]];
    const float* src2 = (const float*)d_in[si[2]];
    const float* src3 = (const float*)d_in[si[3]];
    const float* pos0 = (const float*)d_in[pi[0]];
    const float* pos1 = (const float*)d_in[pi[1]];
    const float* pos2 = (const float*)d_in[pi[2]];
    const float* pos3 = (const float*)d_in[pi[3]];
    const float* level_embed = (const float*)d_in[8];
    const float* Woff  = (const float*)d_in[9];
    const float* boff  = (const float*)d_in[10];
    const float* Wattn = (const float*)d_in[11];
    const float* battn = (const float*)d_in[12];
    const float* Wv = (const float*)d_in[13];
    const float* bv = (const float*)d_in[14];
    const float* Wo = (const float*)d_in[15];
    const float* bo = (const float*)d_in[16];
    const float* g1 = (const float*)d_in[17];
    const float* b1 = (const float*)d_in[18];
    const float* W1  = (const float*)d_in[19];
    const float* bb1 = (const float*)d_in[20];
    const float* W2  = (const float*)d_in[21];
    const float* bb2 = (const float*)d_in[22];
    const float* g2 = (const float*)d_in[23];
    const float* b2 = (const float*)d_in[24];

    // VAL (bf16) lives in the consumed-after-flatten src input buffers.
    ushort_t* V[4] = { (ushort_t*)d_in[si[0]], (ushort_t*)d_in[si[1]],
                       (ushort_t*)d_in[si[2]], (ushort_t*)d_in[si[3]] };

    // X (fp32 state) lives in d_out; the final LN writes the output in place.
    float* X = (float*)d_out;

    const int lHW[4] = {10000, 2500, 625, 169};
    const int lS[4]  = {0, 10000, 12500, 13125};
    const int WOFF_T = 0, WATT_T = 65536, WV_T = 98304, WO_T = 163840,
              W1_T = 229376, W2_T = 491520;
    const size_t WB_ELEMS = 753664;

    // ws = WB (1.507 MB) + chunk region R = RC*3072 bytes.
    const int cand[9] = {1, 2, 4, 8, 16, 32, 64, 128, 256};
    int NC = 256;
    for (int i = 0; i < 9; ++i) {
        int rc = (MROWS + cand[i] - 1) / cand[i];
        size_t need = WB_ELEMS * 2 + (size_t)rc * 3072 + 1024;
        if (need <= ws_size) { NC = cand[i]; break; }
    }
    const int RC = (MROWS + NC - 1) / NC;

    ushort_t* WBl  = (ushort_t*)d_ws;
    char* Rbase    = (char*)d_ws + WB_ELEMS * 2;
    ushort_t* Tqu  = (ushort_t*)Rbase;
    float* OFFc    = (float*)(Rbase + (size_t)RC * 512);
    float* ATTc    = (float*)(Rbase + (size_t)RC * 1536);
    float* PRE     = (float*)(Rbase + (size_t)RC * 2048);
    ushort_t* H1u  = (ushort_t*)Rbase;

    flatten_kernel<<<dim3(313, 8, 8), dim3(32, 8), 0, stream>>>(src0, src1, src2, src3, X);

    for (int l = 0; l < NLAYERS_; ++l) {
        const float* Woff_l  = Woff  + (size_t)l * D_ * 256;
        const float* boff_l  = boff  + (size_t)l * 256;
        const float* Wattn_l = Wattn + (size_t)l * D_ * 128;
        const float* battn_l = battn + (size_t)l * 128;
        const float* Wv_l = Wv + (size_t)l * D_ * D_;
        const float* bv_l = bv + (size_t)l * D_;
        const float* Wo_l = Wo + (size_t)l * D_ * D_;
        const float* bo_l = bo + (size_t)l * D_;
        const float* g1_l = g1 + (size_t)l * D_;
        const float* b1_l = b1 + (size_t)l * D_;
        const float* W1_l  = W1  + (size_t)l * D_ * 1024;
        const float* bb1_l = bb1 + (size_t)l * 1024;
        const float* W2_l  = W2  + (size_t)l * 1024 * D_;
        const float* bb2_l = bb2 + (size_t)l * D_;
        const float* g2_l = g2 + (size_t)l * D_;
        const float* b2_l = b2 + (size_t)l * D_;

        wconv_kernel<<<dim3(256, 6), dim3(32, 8), 0, stream>>>(
            Woff_l, Wattn_l, Wv_l, Wo_l, W1_l, W2_l, WBl);

        // VAL = X @ Wv + bv (bf16, per level/batch into src buffers)
        for (int lv = 0; lv < 4; ++lv) {
            for (int bb = 0; bb < 2; ++bb) {
                int Ml = lHW[lv];
                gemm_m<1, 1><<<dim3((Ml + 127) / 128, 4), 256, 0, stream>>>(
                    X + (size_t)(bb * Q_ + lS[lv]) * D_, WBl + WV_T, bv_l,
                    nullptr, V[lv] + (size_t)bb * lHW[lv] * D_, Ml, 256, 256, 0);
            }
        }

        // attention, chunked
        for (int c = 0; c < NC; ++c) {
            int row0 = c * RC;
            int mc = MROWS - row0; if (mc > RC) mc = RC;
            if (mc <= 0) break;
            int mg = (mc + 127) / 128;
            qmake_kernel<<<(mc * 64 + 255) / 256, 256, 0, stream>>>(
                X, pos0, pos1, pos2, pos3, level_embed, Tqu, row0, mc);
            gemm_m<0, 0><<<dim3(mg, 4), 256, 0, stream>>>(
                Tqu, WBl + WOFF_T, boff_l, nullptr, OFFc, mc, 256, 256, 0);
            gemm_m<0, 0><<<dim3(mg, 2), 256, 0, stream>>>(
                Tqu, WBl + WATT_T, battn_l, nullptr, ATTc, mc, 256, 128, 0);
            sample_kernel<<<(mc + 1) / 2, 256, 0, stream>>>(
                OFFc, ATTc, V[0], V[1], V[2], V[3], Tqu, row0, mc);
            gemm_m<0, 0><<<dim3(mg, 4), 256, 0, stream>>>(
                Tqu, WBl + WO_T, bo_l, X + (size_t)row0 * D_, PRE, mc, 256, 256, 0);
            ln_kernel<<<(mc + 3) / 4, 256, 0, stream>>>(PRE, g1_l, b1_l, X, row0, mc);
        }

        // FFN, chunked (H1u overlays Tqu/OFF/ATT; PRE disjoint)
        for (int c = 0; c < NC; ++c) {
            int row0 = c * RC;
            int mc = MROWS - row0; if (mc > RC) mc = RC;
            if (mc <= 0) break;
            int mg = (mc + 127) / 128;
            float* Xc = X + (size_t)row0 * D_;
            gemm_m<1, 1><<<dim3(mg, 16), 256, 0, stream>>>(
                Xc, WBl + W1_T, bb1_l, nullptr, H1u, mc, 256, 1024, 1);
            gemm_m<0, 0><<<dim3(mg, 4), 256, 0, stream>>>(
                H1u, WBl + W2_T, bb2_l, Xc, PRE, mc, 1024, 256, 0);
            ln_kernel<<<(mc + 3) / 4, 256, 0, stream>>>(PRE, g2_l, b2_l, X, row0, mc);
        }
    }
}

// Round 13
// 2207.336 us; speedup vs baseline: 3.4301x; 1.2973x over previous
//
#include <hip/hip_runtime.h>
#include <math.h>

#define Q_ 13294
#define D_ 256
#define NLAYERS_ 6
#define MROWS 26588
#define MD ((size_t)MROWS * D_)

typedef unsigned short ushort_t;
typedef short bf16x8 __attribute__((ext_vector_type(8)));
typedef float f32x4 __attribute__((ext_vector_type(4)));
typedef ushort_t u16x8 __attribute__((ext_vector_type(8)));

__device__ __forceinline__ float u2f(ushort_t u) {
    return __uint_as_float(((unsigned)u) << 16);
}
__device__ __forceinline__ ushort_t f2bf(float f) {
    unsigned u = __float_as_uint(f);
    return (ushort_t)((u + 0x7fffu + ((u >> 16) & 1u)) >> 16);
}
__device__ __forceinline__ void decode_row(int gr, int& b, int& l, int& p) {
    b = (gr >= Q_) ? 1 : 0;
    int q = gr - b * Q_;
    if (q < 10000)      { l = 0; p = q; }
    else if (q < 12500) { l = 1; p = q - 10000; }
    else if (q < 13125) { l = 2; p = q - 12500; }
    else                { l = 3; p = q - 13125; }
}

// ---------------------------------------------------------------------------
// Flatten src (fp32 transpose): X[b, s_l+p, d] = src_l[b,d,p]
// grid (313, 8, 8), block (32,8)
// ---------------------------------------------------------------------------
__global__ __launch_bounds__(256)
void flatten_kernel(const float* __restrict__ s0, const float* __restrict__ s1,
                    const float* __restrict__ s2, const float* __restrict__ s3,
                    float* __restrict__ X)
{
    const int lHW[4] = {10000, 2500, 625, 169};
    const int lS[4]  = {0, 10000, 12500, 13125};
    int z = blockIdx.z;
    int l = z & 3, b = z >> 2;
    int HW = lHW[l];
    int p0 = blockIdx.x * 32;
    if (p0 >= HW) return;
    int d0 = blockIdx.y * 32;
    const float* src = (l == 0) ? s0 : (l == 1) ? s1 : (l == 2) ? s2 : s3;
    int tx = threadIdx.x, ty = threadIdx.y;
    __shared__ float t[32][33];
    #pragma unroll
    for (int i = 0; i < 4; ++i) {
        int d = d0 + ty + 8 * i, p = p0 + tx;
        t[ty + 8 * i][tx] = (p < HW) ? src[(size_t)(b * D_ + d) * HW + p] : 0.f;
    }
    __syncthreads();
    #pragma unroll
    for (int i = 0; i < 4; ++i) {
        int p = p0 + ty + 8 * i, d = d0 + tx;
        if (p < HW)
            X[(size_t)(b * Q_ + lS[l] + p) * D_ + d] = t[tx][ty + 8 * i];
    }
}

// ---------------------------------------------------------------------------
// Weight transpose+convert for one layer: Wt[n][k](bf16) = W[k][n](fp32)
// Layout puts Woff^T (256 rows) and Wattn^T (128 rows) adjacent -> one
// combined [384][256] block at offset 0.
// grid (256, 6), block (32,8).
// ---------------------------------------------------------------------------
__global__ __launch_bounds__(256)
void wconv_kernel(const float* __restrict__ Woff, const float* __restrict__ Wattn,
                  const float* __restrict__ Wv, const float* __restrict__ Wo,
                  const float* __restrict__ W1, const float* __restrict__ W2,
                  ushort_t* __restrict__ WBl)
{
    const int mk[6] = {256, 256, 256, 256, 256, 1024};
    const int mn[6] = {256, 128, 256, 256, 1024, 256};
    const int mo[6] = {0, 65536, 98304, 163840, 229376, 491520};
    int m = blockIdx.y;
    int K = mk[m], N = mn[m];
    int tilesN = N >> 5;
    int tiles = (K >> 5) * tilesN;
    int tid = blockIdx.x;
    if (tid >= tiles) return;
    int tk = tid / tilesN, tn = tid - tk * tilesN;
    const float* Wsrc = (m == 0) ? Woff : (m == 1) ? Wattn : (m == 2) ? Wv :
                        (m == 3) ? Wo : (m == 4) ? W1 : W2;
    ushort_t* dst = WBl + mo[m];
    __shared__ float t[32][33];
    int tx = threadIdx.x, ty = threadIdx.y;
    #pragma unroll
    for (int i = 0; i < 4; ++i) {
        int k = tk * 32 + ty + 8 * i, n = tn * 32 + tx;
        t[ty + 8 * i][tx] = Wsrc[(size_t)k * N + n];
    }
    __syncthreads();
    #pragma unroll
    for (int i = 0; i < 4; ++i) {
        int n = tn * 32 + ty + 8 * i, k = tk * 32 + tx;
        dst[(size_t)n * K + k] = f2bf(t[tx][ty + 8 * i]);
    }
}

// ---------------------------------------------------------------------------
// qmake: Tq[r, d] (bf16) = X[row0+r, d] + pos_l[b, d, p] + level_embed[l, d]
// 64 threads per row, 4 d's per thread.
// ---------------------------------------------------------------------------
__global__ __launch_bounds__(256)
void qmake_kernel(const float* __restrict__ X,
                  const float* __restrict__ p0_, const float* __restrict__ p1_,
                  const float* __restrict__ p2_, const float* __restrict__ p3_,
                  const float* __restrict__ le,
                  ushort_t* __restrict__ Tq, int row0, int mc)
{
    const int lHW[4] = {10000, 2500, 625, 169};
    int gid = blockIdx.x * 256 + threadIdx.x;
    int r = gid >> 6, d4 = gid & 63;
    if (r >= mc) return;
    int gr = row0 + r;
    int b, l, p;
    decode_row(gr, b, l, p);
    const float* pos = (l == 0) ? p0_ : (l == 1) ? p1_ : (l == 2) ? p2_ : p3_;
    int HW = lHW[l];
    int d = d4 * 4;
    float4 xv = *(const float4*)(X + (size_t)gr * D_ + d);
    ushort4 o;
    o.x = f2bf(xv.x + pos[(size_t)(b * D_ + d + 0) * HW + p] + le[l * D_ + d + 0]);
    o.y = f2bf(xv.y + pos[(size_t)(b * D_ + d + 1) * HW + p] + le[l * D_ + d + 1]);
    o.z = f2bf(xv.z + pos[(size_t)(b * D_ + d + 2) * HW + p] + le[l * D_ + d + 2]);
    o.w = f2bf(xv.w + pos[(size_t)(b * D_ + d + 3) * HW + p] + le[l * D_ + d + 3]);
    *(ushort4*)(Tq + (size_t)r * D_ + d) = o;
}

// ---------------------------------------------------------------------------
// MFMA bf16 GEMM: C[M,N](ldc) = A[M,K] @ Wt^T + bias  (Wt is [N][K] bf16)
// AF=1: A fp32 (converted in staging); AF=0: A bf16.
// CB=1: C bf16; CB=0: C fp32.  Optional fp32 residual Rres (ldc), relu.
// Dual bias: col < nsplit -> bias[col], else bias2[col-nsplit] (block-uniform).
// Tile 128x64, BK=64, 256 thr = 4 waves in 2x2, v_mfma_f32_16x16x32_bf16.
// ---------------------------------------------------------------------------
template<int AF, int CB>
__global__ __launch_bounds__(256)
void gemm_m(const void* __restrict__ Ap, const ushort_t* __restrict__ Wt,
            const float* __restrict__ bias, const float* __restrict__ bias2,
            int nsplit, const float* __restrict__ Rres,
            void* __restrict__ Cp, int M, int K, int ldc, int relu)
{
    __shared__ ushort_t Asm[128][72];
    __shared__ ushort_t Bsm[64][72];
    int t = threadIdx.x;
    int m0 = blockIdx.x * 128, n0 = blockIdx.y * 64;
    int w = t >> 6, lane = t & 63;
    int wm = (w & 1) * 64, wn = (w >> 1) * 32;
    int lm = lane & 15, quad = lane >> 4;
    f32x4 acc[4][2] = {};

    for (int k0 = 0; k0 < K; k0 += 64) {
        if (AF) {
            const float* A = (const float*)Ap;
            int ar = t >> 4, ac = t & 15;
            #pragma unroll
            for (int i = 0; i < 8; ++i) {
                int row = ar + 16 * i;
                int gr = m0 + row;
                float4 av = make_float4(0.f, 0.f, 0.f, 0.f);
                if (gr < M) av = *(const float4*)(A + (size_t)gr * K + k0 + ac * 4);
                ushort4 u;
                u.x = f2bf(av.x); u.y = f2bf(av.y); u.z = f2bf(av.z); u.w = f2bf(av.w);
                *(ushort4*)&Asm[row][ac * 4] = u;
            }
        } else {
            const ushort_t* A = (const ushort_t*)Ap;
            int ar = t >> 3, ac = t & 7;
            #pragma unroll
            for (int i = 0; i < 4; ++i) {
                int row = ar + 32 * i;
                int gr = m0 + row;
                u16x8 av = {};
                if (gr < M) av = *(const u16x8*)(A + (size_t)gr * K + k0 + ac * 8);
                *(u16x8*)&Asm[row][ac * 8] = av;
            }
        }
        {
            int br = t >> 3, bc = t & 7;
            #pragma unroll
            for (int i = 0; i < 2; ++i) {
                int n = br + 32 * i;
                u16x8 bv = *(const u16x8*)(Wt + (size_t)(n0 + n) * K + k0 + bc * 8);
                *(u16x8*)&Bsm[n][bc * 8] = bv;
            }
        }
        __syncthreads();
        #pragma unroll
        for (int ks = 0; ks < 64; ks += 32) {
            bf16x8 af[4], bfr[2];
            #pragma unroll
            for (int i = 0; i < 4; ++i)
                af[i] = *(const bf16x8*)&Asm[wm + i * 16 + lm][ks + quad * 8];
            #pragma unroll
            for (int j = 0; j < 2; ++j)
                bfr[j] = *(const bf16x8*)&Bsm[wn + j * 16 + lm][ks + quad * 8];
            #pragma unroll
            for (int i = 0; i < 4; ++i)
                #pragma unroll
                for (int j = 0; j < 2; ++j)
                    acc[i][j] = __builtin_amdgcn_mfma_f32_16x16x32_bf16(
                        af[i], bfr[j], acc[i][j], 0, 0, 0);
        }
        __syncthreads();
    }

    #pragma unroll
    for (int i = 0; i < 4; ++i) {
        #pragma unroll
        for (int j = 0; j < 2; ++j) {
            int col = n0 + wn + j * 16 + lm;
            float bc = (col < nsplit) ? bias[col] : bias2[col - nsplit];
            #pragma unroll
            for (int r = 0; r < 4; ++r) {
                int row = m0 + wm + i * 16 + quad * 4 + r;
                if (row >= M) continue;
                float v = acc[i][j][r] + bc;
                if (Rres) v += Rres[(size_t)row * ldc + col];
                if (relu) v = fmaxf(v, 0.f);
                if (CB) ((ushort_t*)Cp)[(size_t)row * ldc + col] = f2bf(v);
                else    ((float*)Cp)[(size_t)row * ldc + col] = v;
            }
        }
    }
}

// ---------------------------------------------------------------------------
// LayerNorm chunk: X[row0+r] = LN(PRE[r]) * g + b (fp32). one wave per row.
// ---------------------------------------------------------------------------
__global__ __launch_bounds__(256)
void ln_kernel(const float* __restrict__ P, const float* __restrict__ g,
               const float* __restrict__ b, float* __restrict__ Xo,
               int row0, int mc)
{
    int wave = threadIdx.x >> 6, lane = threadIdx.x & 63;
    int r = blockIdx.x * 4 + wave;
    if (r >= mc) return;
    const float* x = P + (size_t)r * D_;
    float4 v = *(const float4*)(x + lane * 4);
    float s = v.x + v.y + v.z + v.w;
    float sq = v.x * v.x + v.y * v.y + v.z * v.z + v.w * v.w;
    #pragma unroll
    for (int o = 32; o > 0; o >>= 1) {
        s += __shfl_xor(s, o, 64);
        sq += __shfl_xor(sq, o, 64);
    }
    float mean = s * (1.f / 256.f);
    float var = fmaxf(sq * (1.f / 256.f) - mean * mean, 0.f);
    float rs = rsqrtf(var + 1e-5f);
    float4 gv = *(const float4*)(g + lane * 4);
    float4 bv = *(const float4*)(b + lane * 4);
    float4 o;
    o.x = (v.x - mean) * rs * gv.x + bv.x;
    o.y = (v.y - mean) * rs * gv.y + bv.y;
    o.z = (v.z - mean) * rs * gv.z + bv.z;
    o.w = (v.w - mean) * rs * gv.w + bv.w;
    *(float4*)(Xo + (size_t)(row0 + r) * D_ + lane * 4) = o;
}

// ---------------------------------------------------------------------------
// Deformable sampling, descriptor-staged, bank-conflict-free.
// VAL is ONE contiguous [MROWS][256] bf16 buffer (global-row order).
// Block = 2 rows x 128 threads.
// Stage 1 (2 rows x 8 heads x 16 points): softmax via 16-lane shfl; u32
//   element-offset + fused weight per corner -> LDS, per-(row,head) stride 68
//   (68%32=4 -> the 4 heads of a wave land on different banks).
// Stage 2 (2 rows x 8 heads x 16 lanes x 2 ch): u16x2 gathers, unpack, FMA.
// LOG row (ld 384): [0:256) offsets [h][pt][2], [256:384) attn [h][pt]
// ---------------------------------------------------------------------------
__global__ __launch_bounds__(256)
void sample_kernel(const float* __restrict__ LOG,
                   const ushort_t* __restrict__ VAL,
                   ushort_t* __restrict__ OUT, int row0, int mc)
{
    const int lW[4] = {100, 50, 25, 13};
    const int lH[4] = {100, 50, 25, 13};
    const int lS[4] = {0, 10000, 12500, 13125};

    __shared__ unsigned offs[16 * 68];
    __shared__ float    wtsl[16 * 68];

    int tid = threadIdx.x;

    // ---- stage 1: descriptors ----
    {
        int r2 = tid >> 7;
        int j  = tid & 127;
        int h  = j >> 4, pt = j & 15;
        int r  = blockIdx.x * 2 + r2;
        bool ok = (r < mc);
        int gr = row0 + (ok ? r : 0);
        int b, lq, p;
        decode_row(gr, b, lq, p);
        int rw = lW[lq];
        int prow = p / rw, pcol = p - prow * rw;
        float refx = (pcol + 0.5f) / (float)lW[lq];
        float refy = (prow + 0.5f) / (float)lH[lq];

        const float* lg = LOG + (size_t)r * 384;
        float logit = ok ? lg[256 + h * 16 + pt] : 0.f;
        float mx = logit;
        #pragma unroll
        for (int o = 8; o > 0; o >>= 1) mx = fmaxf(mx, __shfl_xor(mx, o, 16));
        float e = __expf(logit - mx);
        float ssum = e;
        #pragma unroll
        for (int o = 8; o > 0; o >>= 1) ssum += __shfl_xor(ssum, o, 16);
        float a = e / ssum;

        int l = pt >> 2;
        int Wl = lW[l], Hl = lH[l];
        unsigned base = (unsigned)((b * Q_ + lS[l]) * 256) + (unsigned)(h * 32);
        float ox = ok ? lg[h * 32 + pt * 2 + 0] : 0.f;
        float oy = ok ? lg[h * 32 + pt * 2 + 1] : 0.f;
        float xf = (refx + ox / (float)Wl) * Wl - 0.5f;
        float yf = (refy + oy / (float)Hl) * Hl - 0.5f;
        xf = fmaxf(fminf(xf, 1.0e6f), -1.0e6f);
        yf = fmaxf(fminf(yf, 1.0e6f), -1.0e6f);
        float x0f = floorf(xf), y0f = floorf(yf);
        float fx = xf - x0f, fy = yf - y0f;
        int x0 = (int)x0f, y0 = (int)y0f;
        int x1 = x0 + 1, y1 = y0 + 1;
        int x0c = min(max(x0, 0), Wl - 1), x1c = min(max(x1, 0), Wl - 1);
        int y0c = min(max(y0, 0), Hl - 1), y1c = min(max(y1, 0), Hl - 1);
        float vx0 = (x0 >= 0 && x0 < Wl) ? 1.f : 0.f;
        float vx1 = (x1 >= 0 && x1 < Wl) ? 1.f : 0.f;
        float vy0 = (y0 >= 0 && y0 < Hl) ? 1.f : 0.f;
        float vy1 = (y1 >= 0 && y1 < Hl) ? 1.f : 0.f;
        int di = (r2 * 8 + h) * 68 + pt * 4;
        offs[di + 0] = base + (unsigned)(y0c * Wl + x0c) * 256u;
        offs[di + 1] = base + (unsigned)(y0c * Wl + x1c) * 256u;
        offs[di + 2] = base + (unsigned)(y1c * Wl + x0c) * 256u;
        offs[di + 3] = base + (unsigned)(y1c * Wl + x1c) * 256u;
        wtsl[di + 0] = a * (1.f - fx) * (1.f - fy) * vx0 * vy0;
        wtsl[di + 1] = a * fx * (1.f - fy) * vx1 * vy0;
        wtsl[di + 2] = a * (1.f - fx) * fy * vx0 * vy1;
        wtsl[di + 3] = a * fx * fy * vx1 * vy1;
    }
    __syncthreads();

    // ---- stage 2: gather ----
    int r2 = tid >> 7;
    int r  = blockIdx.x * 2 + r2;
    if (r >= mc) return;
    int h  = (tid >> 4) & 7;
    int ch = (tid & 15) * 2;
    int dbase = (r2 * 8 + h) * 68;

    float o0 = 0.f, o1 = 0.f;
    #pragma unroll
    for (int pt = 0; pt < 16; ++pt) {
        int di = dbase + pt * 4;
        #pragma unroll
        for (int k = 0; k < 4; ++k) {
            float wk = wtsl[di + k];
            unsigned ov = offs[di + k];
            unsigned v = *(const unsigned*)(VAL + ov + ch);
            float lo = __uint_as_float(v << 16);
            float hi = __uint_as_float(v & 0xffff0000u);
            o0 += wk * lo;
            o1 += wk * hi;
        }
    }
    unsigned pack = ((unsigned)f2bf(o1) << 16) | (unsigned)f2bf(o0);
    *(unsigned*)(OUT + (size_t)r * D_ + h * 32 + ch) = pack;
}

extern "C" void kernel_launch(void* const* d_in, const int* in_sizes, int n_in,
                              void* d_out, int out_size, void* d_ws, size_t ws_size,
                              hipStream_t stream)
{
    // setup_inputs() dict order interleaves src/pos (sizes pair up).
    bool interleaved = (in_sizes[0] == in_sizes[1]);
    int si[4], pi[4];
    for (int i = 0; i < 4; ++i) {
        si[i] = interleaved ? 2 * i : i;
        pi[i] = interleaved ? 2 * i + 1 : 4 + i;
    }
    const float* src0 = (const float*)d_in[si[0]];
    const float* src1 = (const float*)d_in[si[1]];
    const float* src2 = (const float*)d_in[si[2]];
    const float* src3 = (const float*)d_in[si[3]];
    const float* pos0 = (const float*)d_in[pi[0]];
    const float* pos1 = (const float*)d_in[pi[1]];
    const float* pos2 = (const float*)d_in[pi[2]];
    const float* pos3 = (const float*)d_in[pi[3]];
    const float* level_embed = (const float*)d_in[8];
    const float* Woff  = (const float*)d_in[9];
    const float* boff  = (const float*)d_in[10];
    const float* Wattn = (const float*)d_in[11];
    const float* battn = (const float*)d_in[12];
    const float* Wv = (const float*)d_in[13];
    const float* bv = (const float*)d_in[14];
    const float* Wo = (const float*)d_in[15];
    const float* bo = (const float*)d_in[16];
    const float* g1 = (const float*)d_in[17];
    const float* b1 = (const float*)d_in[18];
    const float* W1  = (const float*)d_in[19];
    const float* bb1 = (const float*)d_in[20];
    const float* W2  = (const float*)d_in[21];
    const float* bb2 = (const float*)d_in[22];
    const float* g2 = (const float*)d_in[23];
    const float* b2 = (const float*)d_in[24];

    // VAL (bf16, [MROWS][256] contiguous) lives in src0's buffer (consumed
    // after flatten; 20.5 MB capacity >= 13.6 MB). Harness restores inputs.
    ushort_t* VAL = (ushort_t*)d_in[si[0]];

    // X (fp32 state) lives in d_out; the final LN writes the output in place.
    float* X = (float*)d_out;

    const int WV_T = 98304, WO_T = 163840, W1_T = 229376, W2_T = 491520;
    const size_t WB_ELEMS = 753664;   // Woff^T+Wattn^T combined block at 0

    // ws = WB (1.507 MB) + chunk region R = RC*3072 bytes:
    //   Tqu bf16 [RC,256] @0 | LOG f32 [RC,384] @RC*512 | PRE f32 [RC,256]
    //   @RC*2048.  FFN: H1u bf16 [RC,1024] @0 (overlays Tqu+LOG).
    const int cand[9] = {1, 2, 4, 8, 16, 32, 64, 128, 256};
    int NC = 256;
    for (int i = 0; i < 9; ++i) {
        int rc = (MROWS + cand[i] - 1) / cand[i];
        size_t need = WB_ELEMS * 2 + (size_t)rc * 3072 + 1024;
        if (need <= ws_size) { NC = cand[i]; break; }
    }
    const int RC = (MROWS + NC - 1) / NC;

    ushort_t* WBl  = (ushort_t*)d_ws;
    char* Rbase    = (char*)d_ws + WB_ELEMS * 2;
    ushort_t* Tqu  = (ushort_t*)Rbase;
    float* LOGc    = (float*)(Rbase + (size_t)RC * 512);
    float* PRE     = (float*)(Rbase + (size_t)RC * 2048);
    ushort_t* H1u  = (ushort_t*)Rbase;

    flatten_kernel<<<dim3(313, 8, 8), dim3(32, 8), 0, stream>>>(src0, src1, src2, src3, X);

    const int BIG = 1 << 30;

    for (int l = 0; l < NLAYERS_; ++l) {
        const float* Woff_l  = Woff  + (size_t)l * D_ * 256;
        const float* boff_l  = boff  + (size_t)l * 256;
        const float* Wattn_l = Wattn + (size_t)l * D_ * 128;
        const float* battn_l = battn + (size_t)l * 128;
        const float* Wv_l = Wv + (size_t)l * D_ * D_;
        const float* bv_l = bv + (size_t)l * D_;
        const float* Wo_l = Wo + (size_t)l * D_ * D_;
        const float* bo_l = bo + (size_t)l * D_;
        const float* g1_l = g1 + (size_t)l * D_;
        const float* b1_l = b1 + (size_t)l * D_;
        const float* W1_l  = W1  + (size_t)l * D_ * 1024;
        const float* bb1_l = bb1 + (size_t)l * 1024;
        const float* W2_l  = W2  + (size_t)l * 1024 * D_;
        const float* bb2_l = bb2 + (size_t)l * D_;
        const float* g2_l = g2 + (size_t)l * D_;
        const float* b2_l = b2 + (size_t)l * D_;

        wconv_kernel<<<dim3(256, 6), dim3(32, 8), 0, stream>>>(
            Woff_l, Wattn_l, Wv_l, Wo_l, W1_l, W2_l, WBl);

        // VAL = X @ Wv + bv : ONE GEMM, bf16, global-row order into src0 buf
        gemm_m<1, 1><<<dim3((MROWS + 127) / 128, 4), 256, 0, stream>>>(
            X, WBl + WV_T, bv_l, nullptr, BIG, nullptr, VAL, MROWS, 256, 256, 0);

        // attention, chunked
        for (int c = 0; c < NC; ++c) {
            int row0 = c * RC;
            int mc = MROWS - row0; if (mc > RC) mc = RC;
            if (mc <= 0) break;
            int mg = (mc + 127) / 128;
            qmake_kernel<<<(mc * 64 + 255) / 256, 256, 0, stream>>>(
                X, pos0, pos1, pos2, pos3, level_embed, Tqu, row0, mc);
            // fused OFF+ATT logits: N=384 (Woff^T|Wattn^T combined block)
            gemm_m<0, 0><<<dim3(mg, 6), 256, 0, stream>>>(
                Tqu, WBl, boff_l, battn_l, 256, nullptr, LOGc, mc, 256, 384, 0);
            sample_kernel<<<(mc + 1) / 2, 256, 0, stream>>>(
                LOGc, VAL, Tqu, row0, mc);
            gemm_m<0, 0><<<dim3(mg, 4), 256, 0, stream>>>(
                Tqu, WBl + WO_T, bo_l, nullptr, BIG,
                X + (size_t)row0 * D_, PRE, mc, 256, 256, 0);
            ln_kernel<<<(mc + 3) / 4, 256, 0, stream>>>(PRE, g1_l, b1_l, X, row0, mc);
        }

        // FFN, chunked (H1u overlays Tqu/LOG; PRE disjoint)
        for (int c = 0; c < NC; ++c) {
            int row0 = c * RC;
            int mc = MROWS - row0; if (mc > RC) mc = RC;
            if (mc <= 0) break;
            int mg = (mc + 127) / 128;
            float* Xc = X + (size_t)row0 * D_;
            gemm_m<1, 1><<<dim3(mg, 16), 256, 0, stream>>>(
                Xc, WBl + W1_T, bb1_l, nullptr, BIG, nullptr, H1u, mc, 256, 1024, 1);
            gemm_m<0, 0><<<dim3(mg, 4), 256, 0, stream>>>(
                H1u, WBl + W2_T, bb2_l, nullptr, BIG, Xc, PRE, mc, 1024, 256, 0);
            ln_kernel<<<(mc + 3) / 4, 256, 0, stream>>>(PRE, g2_l, b2_l, X, row0, mc);
        }
    }
}

// Round 14
// 1927.980 us; speedup vs baseline: 3.9271x; 1.1449x over previous
//
#include <hip/hip_runtime.h>
#include <math.h>

#define Q_ 13294
#define D_ 256
#define NLAYERS_ 6
#define MROWS 26588
#define MD ((size_t)MROWS * D_)

typedef unsigned short ushort_t;
typedef short bf16x8 __attribute__((ext_vector_type(8)));
typedef float f32x4 __attribute__((ext_vector_type(4)));
typedef ushort_t u16x8 __attribute__((ext_vector_type(8)));

__device__ __forceinline__ float u2f(ushort_t u) {
    return __uint_as_float(((unsigned)u) << 16);
}
__device__ __forceinline__ ushort_t f2bf(float f) {
    unsigned u = __float_as_uint(f);
    return (ushort_t)((u + 0x7fffu + ((u >> 16) & 1u)) >> 16);
}
__device__ __forceinline__ void decode_row(int gr, int& b, int& l, int& p) {
    b = (gr >= Q_) ? 1 : 0;
    int q = gr - b * Q_;
    if (q < 10000)      { l = 0; p = q; }
    else if (q < 12500) { l = 1; p = q - 10000; }
    else if (q < 13125) { l = 2; p = q - 12500; }
    else                { l = 3; p = q - 13125; }
}

// ---------------------------------------------------------------------------
// Flatten src (fp32 transpose): X[b, s_l+p, d] = src_l[b,d,p]
// grid (313, 8, 8), block (32,8)
// ---------------------------------------------------------------------------
__global__ __launch_bounds__(256)
void flatten_kernel(const float* __restrict__ s0, const float* __restrict__ s1,
                    const float* __restrict__ s2, const float* __restrict__ s3,
                    float* __restrict__ X)
{
    const int lHW[4] = {10000, 2500, 625, 169};
    const int lS[4]  = {0, 10000, 12500, 13125};
    int z = blockIdx.z;
    int l = z & 3, b = z >> 2;
    int HW = lHW[l];
    int p0 = blockIdx.x * 32;
    if (p0 >= HW) return;
    int d0 = blockIdx.y * 32;
    const float* src = (l == 0) ? s0 : (l == 1) ? s1 : (l == 2) ? s2 : s3;
    int tx = threadIdx.x, ty = threadIdx.y;
    __shared__ float t[32][33];
    #pragma unroll
    for (int i = 0; i < 4; ++i) {
        int d = d0 + ty + 8 * i, p = p0 + tx;
        t[ty + 8 * i][tx] = (p < HW) ? src[(size_t)(b * D_ + d) * HW + p] : 0.f;
    }
    __syncthreads();
    #pragma unroll
    for (int i = 0; i < 4; ++i) {
        int p = p0 + ty + 8 * i, d = d0 + tx;
        if (p < HW)
            X[(size_t)(b * Q_ + lS[l] + p) * D_ + d] = t[tx][ty + 8 * i];
    }
}

// ---------------------------------------------------------------------------
// Weight transpose+convert for one layer: Wt[n][k](bf16) = W[k][n](fp32)
// Woff^T (256 rows) and Wattn^T (128 rows) adjacent -> combined [384][256].
// grid (256, 6), block (32,8).
// ---------------------------------------------------------------------------
__global__ __launch_bounds__(256)
void wconv_kernel(const float* __restrict__ Woff, const float* __restrict__ Wattn,
                  const float* __restrict__ Wv, const float* __restrict__ Wo,
                  const float* __restrict__ W1, const float* __restrict__ W2,
                  ushort_t* __restrict__ WBl)
{
    const int mk[6] = {256, 256, 256, 256, 256, 1024};
    const int mn[6] = {256, 128, 256, 256, 1024, 256};
    const int mo[6] = {0, 65536, 98304, 163840, 229376, 491520};
    int m = blockIdx.y;
    int K = mk[m], N = mn[m];
    int tilesN = N >> 5;
    int tiles = (K >> 5) * tilesN;
    int tid = blockIdx.x;
    if (tid >= tiles) return;
    int tk = tid / tilesN, tn = tid - tk * tilesN;
    const float* Wsrc = (m == 0) ? Woff : (m == 1) ? Wattn : (m == 2) ? Wv :
                        (m == 3) ? Wo : (m == 4) ? W1 : W2;
    ushort_t* dst = WBl + mo[m];
    __shared__ float t[32][33];
    int tx = threadIdx.x, ty = threadIdx.y;
    #pragma unroll
    for (int i = 0; i < 4; ++i) {
        int k = tk * 32 + ty + 8 * i, n = tn * 32 + tx;
        t[ty + 8 * i][tx] = Wsrc[(size_t)k * N + n];
    }
    __syncthreads();
    #pragma unroll
    for (int i = 0; i < 4; ++i) {
        int n = tn * 32 + ty + 8 * i, k = tk * 32 + tx;
        dst[(size_t)n * K + k] = f2bf(t[tx][ty + 8 * i]);
    }
}

// ---------------------------------------------------------------------------
// qmake: Tq[r, d] (bf16) = X[row0+r, d] + pos_l[b, d, p] + level_embed[l, d]
// 64 threads per row, 4 d's per thread.
// ---------------------------------------------------------------------------
__global__ __launch_bounds__(256)
void qmake_kernel(const float* __restrict__ X,
                  const float* __restrict__ p0_, const float* __restrict__ p1_,
                  const float* __restrict__ p2_, const float* __restrict__ p3_,
                  const float* __restrict__ le,
                  ushort_t* __restrict__ Tq, int row0, int mc)
{
    const int lHW[4] = {10000, 2500, 625, 169};
    int gid = blockIdx.x * 256 + threadIdx.x;
    int r = gid >> 6, d4 = gid & 63;
    if (r >= mc) return;
    int gr = row0 + r;
    int b, l, p;
    decode_row(gr, b, l, p);
    const float* pos = (l == 0) ? p0_ : (l == 1) ? p1_ : (l == 2) ? p2_ : p3_;
    int HW = lHW[l];
    int d = d4 * 4;
    float4 xv = *(const float4*)(X + (size_t)gr * D_ + d);
    ushort4 o;
    o.x = f2bf(xv.x + pos[(size_t)(b * D_ + d + 0) * HW + p] + le[l * D_ + d + 0]);
    o.y = f2bf(xv.y + pos[(size_t)(b * D_ + d + 1) * HW + p] + le[l * D_ + d + 1]);
    o.z = f2bf(xv.z + pos[(size_t)(b * D_ + d + 2) * HW + p] + le[l * D_ + d + 2]);
    o.w = f2bf(xv.w + pos[(size_t)(b * D_ + d + 3) * HW + p] + le[l * D_ + d + 3]);
    *(ushort4*)(Tq + (size_t)r * D_ + d) = o;
}

// ---------------------------------------------------------------------------
// MFMA bf16 GEMM: C[M,N](ldc) = A[M,K] @ Wt^T + bias  (Wt is [N][K] bf16)
// AF=1: A fp32 (converted in staging); AF=0: A bf16.
// CB=1: C bf16; CB=0: C fp32.  Optional fp32 residual Rres (ldc), relu.
// Dual bias: col < nsplit -> bias[col], else bias2[col-nsplit].
// Tile 128x64, BK=64, 256 thr = 4 waves in 2x2, v_mfma_f32_16x16x32_bf16.
// ---------------------------------------------------------------------------
template<int AF, int CB>
__global__ __launch_bounds__(256)
void gemm_m(const void* __restrict__ Ap, const ushort_t* __restrict__ Wt,
            const float* __restrict__ bias, const float* __restrict__ bias2,
            int nsplit, const float* __restrict__ Rres,
            void* __restrict__ Cp, int M, int K, int ldc, int relu)
{
    __shared__ ushort_t Asm[128][72];
    __shared__ ushort_t Bsm[64][72];
    int t = threadIdx.x;
    int m0 = blockIdx.x * 128, n0 = blockIdx.y * 64;
    int w = t >> 6, lane = t & 63;
    int wm = (w & 1) * 64, wn = (w >> 1) * 32;
    int lm = lane & 15, quad = lane >> 4;
    f32x4 acc[4][2] = {};

    for (int k0 = 0; k0 < K; k0 += 64) {
        if (AF) {
            const float* A = (const float*)Ap;
            int ar = t >> 4, ac = t & 15;
            #pragma unroll
            for (int i = 0; i < 8; ++i) {
                int row = ar + 16 * i;
                int gr = m0 + row;
                float4 av = make_float4(0.f, 0.f, 0.f, 0.f);
                if (gr < M) av = *(const float4*)(A + (size_t)gr * K + k0 + ac * 4);
                ushort4 u;
                u.x = f2bf(av.x); u.y = f2bf(av.y); u.z = f2bf(av.z); u.w = f2bf(av.w);
                *(ushort4*)&Asm[row][ac * 4] = u;
            }
        } else {
            const ushort_t* A = (const ushort_t*)Ap;
            int ar = t >> 3, ac = t & 7;
            #pragma unroll
            for (int i = 0; i < 4; ++i) {
                int row = ar + 32 * i;
                int gr = m0 + row;
                u16x8 av = {};
                if (gr < M) av = *(const u16x8*)(A + (size_t)gr * K + k0 + ac * 8);
                *(u16x8*)&Asm[row][ac * 8] = av;
            }
        }
        {
            int br = t >> 3, bc = t & 7;
            #pragma unroll
            for (int i = 0; i < 2; ++i) {
                int n = br + 32 * i;
                u16x8 bv = *(const u16x8*)(Wt + (size_t)(n0 + n) * K + k0 + bc * 8);
                *(u16x8*)&Bsm[n][bc * 8] = bv;
            }
        }
        __syncthreads();
        #pragma unroll
        for (int ks = 0; ks < 64; ks += 32) {
            bf16x8 af[4], bfr[2];
            #pragma unroll
            for (int i = 0; i < 4; ++i)
                af[i] = *(const bf16x8*)&Asm[wm + i * 16 + lm][ks + quad * 8];
            #pragma unroll
            for (int j = 0; j < 2; ++j)
                bfr[j] = *(const bf16x8*)&Bsm[wn + j * 16 + lm][ks + quad * 8];
            #pragma unroll
            for (int i = 0; i < 4; ++i)
                #pragma unroll
                for (int j = 0; j < 2; ++j)
                    acc[i][j] = __builtin_amdgcn_mfma_f32_16x16x32_bf16(
                        af[i], bfr[j], acc[i][j], 0, 0, 0);
        }
        __syncthreads();
    }

    #pragma unroll
    for (int i = 0; i < 4; ++i) {
        #pragma unroll
        for (int j = 0; j < 2; ++j) {
            int col = n0 + wn + j * 16 + lm;
            float bc = (col < nsplit) ? bias[col] : bias2[col - nsplit];
            #pragma unroll
            for (int r = 0; r < 4; ++r) {
                int row = m0 + wm + i * 16 + quad * 4 + r;
                if (row >= M) continue;
                float v = acc[i][j][r] + bc;
                if (Rres) v += Rres[(size_t)row * ldc + col];
                if (relu) v = fmaxf(v, 0.f);
                if (CB) ((ushort_t*)Cp)[(size_t)row * ldc + col] = f2bf(v);
                else    ((float*)Cp)[(size_t)row * ldc + col] = v;
            }
        }
    }
}

// ---------------------------------------------------------------------------
// LayerNorm chunk: X[row0+r] = LN(PRE[r]) * g + b (fp32). one wave per row.
// ---------------------------------------------------------------------------
__global__ __launch_bounds__(256)
void ln_kernel(const float* __restrict__ P, const float* __restrict__ g,
               const float* __restrict__ b, float* __restrict__ Xo,
               int row0, int mc)
{
    int wave = threadIdx.x >> 6, lane = threadIdx.x & 63;
    int r = blockIdx.x * 4 + wave;
    if (r >= mc) return;
    const float* x = P + (size_t)r * D_;
    float4 v = *(const float4*)(x + lane * 4);
    float s = v.x + v.y + v.z + v.w;
    float sq = v.x * v.x + v.y * v.y + v.z * v.z + v.w * v.w;
    #pragma unroll
    for (int o = 32; o > 0; o >>= 1) {
        s += __shfl_xor(s, o, 64);
        sq += __shfl_xor(sq, o, 64);
    }
    float mean = s * (1.f / 256.f);
    float var = fmaxf(sq * (1.f / 256.f) - mean * mean, 0.f);
    float rs = rsqrtf(var + 1e-5f);
    float4 gv = *(const float4*)(g + lane * 4);
    float4 bv = *(const float4*)(b + lane * 4);
    float4 o;
    o.x = (v.x - mean) * rs * gv.x + bv.x;
    o.y = (v.y - mean) * rs * gv.y + bv.y;
    o.z = (v.z - mean) * rs * gv.z + bv.z;
    o.w = (v.w - mean) * rs * gv.w + bv.w;
    *(float4*)(Xo + (size_t)(row0 + r) * D_ + lane * 4) = o;
}

// ---------------------------------------------------------------------------
// Deformable sampling, descriptor-staged, conflict-free, high-MLP stage 2.
// VAL is ONE contiguous [MROWS][256] bf16 buffer (global-row order).
// Block = 2 rows x 128 threads.
// Stage 1: softmax via 16-lane shfl; u32 element-offset + fused weight per
//   corner -> LDS at per-(row,head) stride 68 (bank-conflict-free).
// Stage 2: per group of 4 points, ds_read_b128 descriptors then 16
//   independent global u16x2 gathers in flight (explicit arrays force MLP).
// LOG row (ld 384): [0:256) offsets [h][pt][2], [256:384) attn [h][pt]
// ---------------------------------------------------------------------------
__global__ __launch_bounds__(256)
void sample_kernel(const float* __restrict__ LOG,
                   const ushort_t* __restrict__ VAL,
                   ushort_t* __restrict__ OUT, int row0, int mc)
{
    const int lW[4] = {100, 50, 25, 13};
    const int lH[4] = {100, 50, 25, 13};
    const int lS[4] = {0, 10000, 12500, 13125};

    __shared__ unsigned offs[16 * 68];
    __shared__ float    wtsl[16 * 68];

    int tid = threadIdx.x;

    // ---- stage 1: descriptors ----
    {
        int r2 = tid >> 7;
        int j  = tid & 127;
        int h  = j >> 4, pt = j & 15;
        int r  = blockIdx.x * 2 + r2;
        bool ok = (r < mc);
        int gr = row0 + (ok ? r : 0);
        int b, lq, p;
        decode_row(gr, b, lq, p);
        int rw = lW[lq];
        int prow = p / rw, pcol = p - prow * rw;
        float refx = (pcol + 0.5f) / (float)lW[lq];
        float refy = (prow + 0.5f) / (float)lH[lq];

        const float* lg = LOG + (size_t)r * 384;
        float logit = ok ? lg[256 + h * 16 + pt] : 0.f;
        float mx = logit;
        #pragma unroll
        for (int o = 8; o > 0; o >>= 1) mx = fmaxf(mx, __shfl_xor(mx, o, 16));
        float e = __expf(logit - mx);
        float ssum = e;
        #pragma unroll
        for (int o = 8; o > 0; o >>= 1) ssum += __shfl_xor(ssum, o, 16);
        float a = e / ssum;

        int l = pt >> 2;
        int Wl = lW[l], Hl = lH[l];
        unsigned base = (unsigned)((b * Q_ + lS[l]) * 256) + (unsigned)(h * 32);
        float ox = ok ? lg[h * 32 + pt * 2 + 0] : 0.f;
        float oy = ok ? lg[h * 32 + pt * 2 + 1] : 0.f;
        float xf = (refx + ox / (float)Wl) * Wl - 0.5f;
        float yf = (refy + oy / (float)Hl) * Hl - 0.5f;
        xf = fmaxf(fminf(xf, 1.0e6f), -1.0e6f);
        yf = fmaxf(fminf(yf, 1.0e6f), -1.0e6f);
        float x0f = floorf(xf), y0f = floorf(yf);
        float fx = xf - x0f, fy = yf - y0f;
        int x0 = (int)x0f, y0 = (int)y0f;
        int x1 = x0 + 1, y1 = y0 + 1;
        int x0c = min(max(x0, 0), Wl - 1), x1c = min(max(x1, 0), Wl - 1);
        int y0c = min(max(y0, 0), Hl - 1), y1c = min(max(y1, 0), Hl - 1);
        float vx0 = (x0 >= 0 && x0 < Wl) ? 1.f : 0.f;
        float vx1 = (x1 >= 0 && x1 < Wl) ? 1.f : 0.f;
        float vy0 = (y0 >= 0 && y0 < Hl) ? 1.f : 0.f;
        float vy1 = (y1 >= 0 && y1 < Hl) ? 1.f : 0.f;
        int di = (r2 * 8 + h) * 68 + pt * 4;
        offs[di + 0] = base + (unsigned)(y0c * Wl + x0c) * 256u;
        offs[di + 1] = base + (unsigned)(y0c * Wl + x1c) * 256u;
        offs[di + 2] = base + (unsigned)(y1c * Wl + x0c) * 256u;
        offs[di + 3] = base + (unsigned)(y1c * Wl + x1c) * 256u;
        wtsl[di + 0] = a * (1.f - fx) * (1.f - fy) * vx0 * vy0;
        wtsl[di + 1] = a * fx * (1.f - fy) * vx1 * vy0;
        wtsl[di + 2] = a * (1.f - fx) * fy * vx0 * vy1;
        wtsl[di + 3] = a * fx * fy * vx1 * vy1;
    }
    __syncthreads();

    // ---- stage 2: gather with 16 loads in flight ----
    int r2 = tid >> 7;
    int r  = blockIdx.x * 2 + r2;
    if (r >= mc) return;
    int h  = (tid >> 4) & 7;
    int ch = (tid & 15) * 2;
    int dbase = (r2 * 8 + h) * 68;
    const ushort_t* Vch = VAL + ch;

    float o0 = 0.f, o1 = 0.f;
    #pragma unroll
    for (int pg = 0; pg < 16; pg += 4) {
        uint4 o4[4];
        float4 w4[4];
        #pragma unroll
        for (int j = 0; j < 4; ++j) {
            o4[j] = *(const uint4*)&offs[dbase + (pg + j) * 4];
            w4[j] = *(const float4*)&wtsl[dbase + (pg + j) * 4];
        }
        unsigned v[16];
        #pragma unroll
        for (int j = 0; j < 4; ++j) {
            v[j * 4 + 0] = *(const unsigned*)(Vch + o4[j].x);
            v[j * 4 + 1] = *(const unsigned*)(Vch + o4[j].y);
            v[j * 4 + 2] = *(const unsigned*)(Vch + o4[j].z);
            v[j * 4 + 3] = *(const unsigned*)(Vch + o4[j].w);
        }
        #pragma unroll
        for (int j = 0; j < 4; ++j) {
            const float* wj = (const float*)&w4[j];
            #pragma unroll
            for (int k = 0; k < 4; ++k) {
                unsigned vv = v[j * 4 + k];
                o0 += wj[k] * __uint_as_float(vv << 16);
                o1 += wj[k] * __uint_as_float(vv & 0xffff0000u);
            }
        }
    }
    unsigned pack = ((unsigned)f2bf(o1) << 16) | (unsigned)f2bf(o0);
    *(unsigned*)(OUT + (size_t)r * D_ + h * 32 + ch) = pack;
}

extern "C" void kernel_launch(void* const* d_in, const int* in_sizes, int n_in,
                              void* d_out, int out_size, void* d_ws, size_t ws_size,
                              hipStream_t stream)
{
    // setup_inputs() dict order interleaves src/pos (sizes pair up).
    bool interleaved = (in_sizes[0] == in_sizes[1]);
    int si[4], pi[4];
    for (int i = 0; i < 4; ++i) {
        si[i] = interleaved ? 2 * i : i;
        pi[i] = interleaved ? 2 * i + 1 : 4 + i;
    }
    const float* src0 = (const float*)d_in[si[0]];
    const float* src1 = (const float*)d_in[si[1]];
    const float* src2 = (const float*)d_in[si[2]];
    const float* src3 = (const float*)d_in[si[3]];
    const float* pos0 = (const float*)d_in[pi[0]];
    const float* pos1 = (const float*)d_in[pi[1]];
    const float* pos2 = (const float*)d_in[pi[2]];
    const float* pos3 = (const float*)d_in[pi[3]];
    const float* level_embed = (const float*)d_in[8];
    const float* Woff  = (const float*)d_in[9];
    const float* boff  = (const float*)d_in[10];
    const float* Wattn = (const float*)d_in[11];
    const float* battn = (const float*)d_in[12];
    const float* Wv = (const float*)d_in[13];
    const float* bv = (const float*)d_in[14];
    const float* Wo = (const float*)d_in[15];
    const float* bo = (const float*)d_in[16];
    const float* g1 = (const float*)d_in[17];
    const float* b1 = (const float*)d_in[18];
    const float* W1  = (const float*)d_in[19];
    const float* bb1 = (const float*)d_in[20];
    const float* W2  = (const float*)d_in[21];
    const float* bb2 = (const float*)d_in[22];
    const float* g2 = (const float*)d_in[23];
    const float* b2 = (const float*)d_in[24];

    // VAL (bf16, [MROWS][256] contiguous) lives in src0's buffer (consumed
    // after flatten; 20.5 MB capacity >= 13.6 MB). Harness restores inputs.
    ushort_t* VAL = (ushort_t*)d_in[si[0]];

    // X (fp32 state) lives in d_out; the final LN writes the output in place.
    float* X = (float*)d_out;

    const int WV_T = 98304, WO_T = 163840, W1_T = 229376, W2_T = 491520;
    const size_t WB_ELEMS = 753664;   // Woff^T+Wattn^T combined block at 0

    // ws = WB (1.507 MB) + chunk region R = RC*3072 bytes:
    //   Tqu bf16 [RC,256] @0 | LOG f32 [RC,384] @RC*512 | PRE f32 [RC,256]
    //   @RC*2048.  FFN: H1u bf16 [RC,1024] @0 (overlays Tqu+LOG).
    const int cand[9] = {1, 2, 4, 8, 16, 32, 64, 128, 256};
    int NC = 256;
    for (int i = 0; i < 9; ++i) {
        int rc = (MROWS + cand[i] - 1) / cand[i];
        size_t need = WB_ELEMS * 2 + (size_t)rc * 3072 + 1024;
        if (need <= ws_size) { NC = cand[i]; break; }
    }
    const int RC = (MROWS + NC - 1) / NC;

    ushort_t* WBl  = (ushort_t*)d_ws;
    char* Rbase    = (char*)d_ws + WB_ELEMS * 2;
    ushort_t* Tqu  = (ushort_t*)Rbase;
    float* LOGc    = (float*)(Rbase + (size_t)RC * 512);
    float* PRE     = (float*)(Rbase + (size_t)RC * 2048);
    ushort_t* H1u  = (ushort_t*)Rbase;

    flatten_kernel<<<dim3(313, 8, 8), dim3(32, 8), 0, stream>>>(src0, src1, src2, src3, X);

    const int BIG = 1 << 30;

    for (int l = 0; l < NLAYERS_; ++l) {
        const float* Woff_l  = Woff  + (size_t)l * D_ * 256;
        const float* boff_l  = boff  + (size_t)l * 256;
        const float* Wattn_l = Wattn + (size_t)l * D_ * 128;
        const float* battn_l = battn + (size_t)l * 128;
        const float* Wv_l = Wv + (size_t)l * D_ * D_;
        const float* bv_l = bv + (size_t)l * D_;
        const float* Wo_l = Wo + (size_t)l * D_ * D_;
        const float* bo_l = bo + (size_t)l * D_;
        const float* g1_l = g1 + (size_t)l * D_;
        const float* b1_l = b1 + (size_t)l * D_;
        const float* W1_l  = W1  + (size_t)l * D_ * 1024;
        const float* bb1_l = bb1 + (size_t)l * 1024;
        const float* W2_l  = W2  + (size_t)l * 1024 * D_;
        const float* bb2_l = bb2 + (size_t)l * D_;
        const float* g2_l = g2 + (size_t)l * D_;
        const float* b2_l = b2 + (size_t)l * D_;

        wconv_kernel<<<dim3(256, 6), dim3(32, 8), 0, stream>>>(
            Woff_l, Wattn_l, Wv_l, Wo_l, W1_l, W2_l, WBl);

        // VAL = X @ Wv + bv : ONE GEMM, bf16, global-row order into src0 buf
        gemm_m<1, 1><<<dim3((MROWS + 127) / 128, 4), 256, 0, stream>>>(
            X, WBl + WV_T, bv_l, nullptr, BIG, nullptr, VAL, MROWS, 256, 256, 0);

        // attention, chunked
        for (int c = 0; c < NC; ++c) {
            int row0 = c * RC;
            int mc = MROWS - row0; if (mc > RC) mc = RC;
            if (mc <= 0) break;
            int mg = (mc + 127) / 128;
            qmake_kernel<<<(mc * 64 + 255) / 256, 256, 0, stream>>>(
                X, pos0, pos1, pos2, pos3, level_embed, Tqu, row0, mc);
            // fused OFF+ATT logits: N=384 (Woff^T|Wattn^T combined block)
            gemm_m<0, 0><<<dim3(mg, 6), 256, 0, stream>>>(
                Tqu, WBl, boff_l, battn_l, 256, nullptr, LOGc, mc, 256, 384, 0);
            sample_kernel<<<(mc + 1) / 2, 256, 0, stream>>>(
                LOGc, VAL, Tqu, row0, mc);
            gemm_m<0, 0><<<dim3(mg, 4), 256, 0, stream>>>(
                Tqu, WBl + WO_T, bo_l, nullptr, BIG,
                X + (size_t)row0 * D_, PRE, mc, 256, 256, 0);
            ln_kernel<<<(mc + 3) / 4, 256, 0, stream>>>(PRE, g1_l, b1_l, X, row0, mc);
        }

        // FFN, chunked (H1u overlays Tqu/LOG; PRE disjoint)
        for (int c = 0; c < NC; ++c) {
            int row0 = c * RC;
            int mc = MROWS - row0; if (mc > RC) mc = RC;
            if (mc <= 0) break;
            int mg = (mc + 127) / 128;
            float* Xc = X + (size_t)row0 * D_;
            gemm_m<1, 1><<<dim3(mg, 16), 256, 0, stream>>>(
                Xc, WBl + W1_T, bb1_l, nullptr, BIG, nullptr, H1u, mc, 256, 1024, 1);
            gemm_m<0, 0><<<dim3(mg, 4), 256, 0, stream>>>(
                H1u, WBl + W2_T, bb2_l, nullptr, BIG, Xc, PRE, mc, 1024, 256, 0);
            ln_kernel<<<(mc + 3) / 4, 256, 0, stream>>>(PRE, g2_l, b2_l, X, row0, mc);
        }
    }
}